// Round 1
// baseline (469.314 us; speedup 1.0000x reference)
//
#include <hip/hip_runtime.h>
#include <math.h>

#define NN 100000
#define EE 600000
#define DD 128
#define GG 256
#define EPSV 1e-5f

// ---------------- workspace layout (bytes) ----------------
#define OFF_A1      0
#define OFF_B1      131072
#define OFF_A2      262144
#define OFF_B2      393216
#define OFF_DEG     524288      // N ints
#define OFF_ROWPTR  924288      // N+1 ints
#define OFF_CURSOR  1324352     // N ints
#define OFF_BSUMS   1724352     // <=512 ints
#define OFF_BOFFS   1726400     // <=512 ints
#define OFF_ELIST   1728448     // E ints  -> end ~4.13 MB

__device__ __forceinline__ int lower_bound_i(const int* __restrict__ a, int n, int v) {
    int lo = 0, hi = n;
    while (lo < hi) { int mid = (lo + hi) >> 1; if (a[mid] < v) lo = mid + 1; else hi = mid; }
    return lo;
}

// ---------------- per-graph stats -> affine (h = A*x + B) ----------------
// one block per graph; batch is sorted so the graph is a contiguous row range.
__global__ __launch_bounds__(256) void stats_kernel(
    const float* __restrict__ X, const int* __restrict__ batch,
    const float* __restrict__ w, const float* __restrict__ bb, const float* __restrict__ ms,
    float* __restrict__ A, float* __restrict__ B)
{
    int g = blockIdx.x;
    __shared__ int rng[2];
    if (threadIdx.x == 0) { rng[0] = lower_bound_i(batch, NN, g); rng[1] = lower_bound_i(batch, NN, g + 1); }
    __syncthreads();
    int start = rng[0], cnt = rng[1] - rng[0];

    const float4* X4 = (const float4*)X;
    float s[4] = {0.f, 0.f, 0.f, 0.f}, q[4] = {0.f, 0.f, 0.f, 0.f};
    int base = start * 32, total = cnt * 32;
    for (int off = threadIdx.x; off < total; off += 256) {
        float4 v = X4[base + off];
        s[0] += v.x; s[1] += v.y; s[2] += v.z; s[3] += v.w;
        q[0] += v.x * v.x; q[1] += v.y * v.y; q[2] += v.z * v.z; q[3] += v.w * v.w;
    }
    __shared__ float ls[256 * 4];
    __shared__ float lq[256 * 4];
    #pragma unroll
    for (int k = 0; k < 4; k++) { ls[threadIdx.x * 4 + k] = s[k]; lq[threadIdx.x * 4 + k] = q[k]; }
    __syncthreads();
    if (threadIdx.x < 32) {
        // threads t, t+32, ..., t+224 accumulated the same 4 features (t*4 .. t*4+3)
        for (int j = 1; j < 8; j++) {
            int o = (threadIdx.x + 32 * j) * 4;
            #pragma unroll
            for (int k = 0; k < 4; k++) { s[k] += ls[o + k]; q[k] += lq[o + k]; }
        }
        float c = (float)(cnt > 0 ? cnt : 1);
        float inv_c = 1.0f / c;
        #pragma unroll
        for (int k = 0; k < 4; k++) {
            int d = threadIdx.x * 4 + k;
            float m  = s[k] * inv_c;
            float qm = q[k] * inv_c;
            float sc = ms[d];
            // var of (x - m*sc): E[x^2] - m^2*sc*(2-sc)
            float var = qm - m * m * sc * (2.0f - sc);
            float inv = rsqrtf(var + EPSV);
            float Ad = w[d] * inv;
            A[g * DD + d] = Ad;
            B[g * DD + d] = bb[d] - Ad * m * sc;
        }
    }
}

// ---------------- CSR build ----------------
__global__ __launch_bounds__(256) void deg_kernel(const int* __restrict__ dst, int* __restrict__ deg) {
    int e = blockIdx.x * 256 + threadIdx.x;
    if (e < EE) atomicAdd(&deg[dst[e]], 1);
}

__global__ __launch_bounds__(256) void scan1(const int* __restrict__ deg, int* __restrict__ bsums) {
    int b = blockIdx.x, t = threadIdx.x;
    int base = b * 1024 + t * 4;
    int v = 0;
    #pragma unroll
    for (int k = 0; k < 4; k++) { int i = base + k; if (i < NN) v += deg[i]; }
    __shared__ int sd[256];
    sd[t] = v; __syncthreads();
    for (int off = 128; off > 0; off >>= 1) { if (t < off) sd[t] += sd[t + off]; __syncthreads(); }
    if (t == 0) bsums[b] = sd[0];
}

__global__ __launch_bounds__(128) void scan2(const int* __restrict__ bsums, int* __restrict__ boffs, int nb) {
    int t = threadIdx.x;
    int v = (t < nb) ? bsums[t] : 0;
    __shared__ int sd[128];
    sd[t] = v; __syncthreads();
    for (int off = 1; off < 128; off <<= 1) {
        int a = (t >= off) ? sd[t - off] : 0;
        __syncthreads();
        sd[t] += a;
        __syncthreads();
    }
    if (t < nb) boffs[t] = sd[t] - v;   // exclusive
}

__global__ __launch_bounds__(256) void scan3(const int* __restrict__ deg, const int* __restrict__ boffs,
                                             int* __restrict__ rowptr) {
    int b = blockIdx.x, t = threadIdx.x;
    int base = b * 1024 + t * 4;
    int d0 = 0, d1 = 0, d2 = 0, d3 = 0;
    if (base     < NN) d0 = deg[base];
    if (base + 1 < NN) d1 = deg[base + 1];
    if (base + 2 < NN) d2 = deg[base + 2];
    if (base + 3 < NN) d3 = deg[base + 3];
    int tsum = d0 + d1 + d2 + d3;
    __shared__ int sd[256];
    sd[t] = tsum; __syncthreads();
    for (int off = 1; off < 256; off <<= 1) {
        int a = (t >= off) ? sd[t - off] : 0;
        __syncthreads();
        sd[t] += a;
        __syncthreads();
    }
    int exc = sd[t] - tsum + boffs[b];
    if (base     < NN) rowptr[base]     = exc;
    if (base + 1 < NN) rowptr[base + 1] = exc + d0;
    if (base + 2 < NN) rowptr[base + 2] = exc + d0 + d1;
    if (base + 3 < NN) rowptr[base + 3] = exc + d0 + d1 + d2;
    if (b == 0 && t == 0) rowptr[NN] = EE;
}

__global__ __launch_bounds__(256) void cursor_copy(const int* __restrict__ rowptr, int* __restrict__ cursor) {
    int i = blockIdx.x * 256 + threadIdx.x;
    if (i < NN) cursor[i] = rowptr[i];
}

__global__ __launch_bounds__(256) void fill_kernel(const int* __restrict__ src, const int* __restrict__ dst,
                                                   int* __restrict__ cursor, int* __restrict__ elist) {
    int e = blockIdx.x * 256 + threadIdx.x;
    if (e < EE) {
        int p = atomicAdd(&cursor[dst[e]], 1);
        elist[p] = src[e];
    }
}

// ---------------- gather-max aggregation (h1 computed on the fly) ----------------
// one block (128 threads) per dst node; writes agg into H (= d_out staging).
__global__ __launch_bounds__(128) void agg_kernel(
    const float* __restrict__ X, const int* __restrict__ batch,
    const float* __restrict__ A1, const float* __restrict__ B1,
    const int* __restrict__ rowptr, const int* __restrict__ elist, float* __restrict__ H)
{
    int i = blockIdx.x, d = threadIdx.x;
    int beg = rowptr[i], end = rowptr[i + 1];
    float acc = -INFINITY;
    for (int e = beg; e < end; e++) {
        int s = elist[e];
        int g = batch[s];
        float v = fmaf(A1[g * DD + d], X[s * DD + d], B1[g * DD + d]);
        acc = fmaxf(acc, v);
    }
    if (end == beg) acc = 0.f;   // PyG fills empty segments with 0
    H[i * DD + d] = acc;
}

// ---------------- fused GEMM: h2 = relu(x + agg@wl^T + bl + h1@wr^T) ----------------
// combined [N,256] @ [256,128]; 32 rows per block, 4x4 register tile per thread.
// H is both input (agg rows, block-local, read into LDS first) and output (h2).
#define GR 32
__global__ __launch_bounds__(256) void gemm_kernel(
    const float* __restrict__ X, const int* __restrict__ batch,
    const float* __restrict__ A1, const float* __restrict__ B1,
    const float* __restrict__ wl, const float* __restrict__ blv, const float* __restrict__ wr,
    float* H)
{
    __shared__ float u[GR * 260];     // 32 rows x 256 (stride 260) = 33.3 KB
    __shared__ float wt[DD * 36];     // 128 cols x 32-k chunk (stride 36) = 18.4 KB
    int i0 = blockIdx.x * GR;
    int tid = threadIdx.x;

    // load u tile: cols 0..127 = agg (from H), 128..255 = h1 = A1*x+B1
    for (int t = tid; t < GR * 64; t += 256) {
        int r = t >> 6; int c4 = t & 63;
        int i = i0 + r;
        float4 v;
        if (c4 < 32) {
            v = ((const float4*)H)[i * 32 + c4];
        } else {
            int cc = c4 - 32;
            float4 xv = ((const float4*)X)[i * 32 + cc];
            int g = batch[i];
            float4 a = ((const float4*)A1)[g * 32 + cc];
            float4 b = ((const float4*)B1)[g * 32 + cc];
            v.x = fmaf(a.x, xv.x, b.x); v.y = fmaf(a.y, xv.y, b.y);
            v.z = fmaf(a.z, xv.z, b.z); v.w = fmaf(a.w, xv.w, b.w);
        }
        *((float4*)&u[r * 260 + c4 * 4]) = v;
    }

    float acc[4][4];
    #pragma unroll
    for (int rr = 0; rr < 4; rr++)
        #pragma unroll
        for (int cc = 0; cc < 4; cc++) acc[rr][cc] = 0.f;

    int r0 = (tid >> 5) * 4;     // 8 row-groups of 4
    int c0 = tid & 31;           // cols c0, c0+32, c0+64, c0+96

    for (int kc = 0; kc < 8; kc++) {                 // 8 chunks of K=32
        __syncthreads();                             // protects wt (and u on first iter)
        const float* Wsrc = (kc < 4) ? wl : wr;
        int kb4 = (kc & 3) * 8;                      // float4 offset within 128-wide row
        for (int t = tid; t < DD * 8; t += 256) {
            int j = t >> 3; int k4 = t & 7;
            float4 v = ((const float4*)Wsrc)[j * 32 + kb4 + k4];
            *((float4*)&wt[j * 36 + k4 * 4]) = v;
        }
        __syncthreads();
        #pragma unroll
        for (int k4 = 0; k4 < 8; k4++) {
            float4 uu[4], ww[4];
            #pragma unroll
            for (int rr = 0; rr < 4; rr++)
                uu[rr] = *((const float4*)&u[(r0 + rr) * 260 + (kc * 8 + k4) * 4]);
            #pragma unroll
            for (int cc = 0; cc < 4; cc++)
                ww[cc] = *((const float4*)&wt[(c0 + 32 * cc) * 36 + k4 * 4]);
            #pragma unroll
            for (int rr = 0; rr < 4; rr++)
                #pragma unroll
                for (int cc = 0; cc < 4; cc++)
                    acc[rr][cc] = fmaf(uu[rr].x, ww[cc].x,
                                   fmaf(uu[rr].y, ww[cc].y,
                                    fmaf(uu[rr].z, ww[cc].z,
                                     fmaf(uu[rr].w, ww[cc].w, acc[rr][cc]))));
        }
    }

    // epilogue: h2 = relu(x + bl + gemm); overwrite H rows (agg already consumed into LDS)
    #pragma unroll
    for (int rr = 0; rr < 4; rr++) {
        int i = i0 + r0 + rr;
        #pragma unroll
        for (int cc = 0; cc < 4; cc++) {
            int j = c0 + 32 * cc;
            float v = X[i * DD + j] + blv[j] + acc[rr][cc];
            H[i * DD + j] = v > 0.f ? v : 0.f;
        }
    }
}

// ---------------- final norm apply (in place on d_out) ----------------
__global__ __launch_bounds__(256) void apply_kernel(float* __restrict__ H, const int* __restrict__ batch,
                                                    const float* __restrict__ A2, const float* __restrict__ B2) {
    int f = blockIdx.x * 256 + threadIdx.x;    // float4 index
    if (f >= NN * 32) return;
    int i = f >> 5, c = f & 31;
    int g = batch[i];
    float4 v = ((float4*)H)[f];
    float4 a = ((const float4*)A2)[g * 32 + c];
    float4 b = ((const float4*)B2)[g * 32 + c];
    v.x = fmaf(a.x, v.x, b.x); v.y = fmaf(a.y, v.y, b.y);
    v.z = fmaf(a.z, v.z, b.z); v.w = fmaf(a.w, v.w, b.w);
    ((float4*)H)[f] = v;
}

extern "C" void kernel_launch(void* const* d_in, const int* in_sizes, int n_in,
                              void* d_out, int out_size, void* d_ws, size_t ws_size,
                              hipStream_t stream) {
    const float* x    = (const float*)d_in[0];
    const int*   ei   = (const int*)d_in[1];     // [2, E] int32
    const int*   batch= (const int*)d_in[2];
    const float* n1w  = (const float*)d_in[3];
    const float* n1b  = (const float*)d_in[4];
    const float* n1ms = (const float*)d_in[5];
    const float* n2w  = (const float*)d_in[6];
    const float* n2b  = (const float*)d_in[7];
    const float* n2ms = (const float*)d_in[8];
    const float* wl   = (const float*)d_in[9];
    const float* bl   = (const float*)d_in[10];
    const float* wr   = (const float*)d_in[11];
    float* out = (float*)d_out;

    char* w = (char*)d_ws;
    float* A1     = (float*)(w + OFF_A1);
    float* B1     = (float*)(w + OFF_B1);
    float* A2     = (float*)(w + OFF_A2);
    float* B2     = (float*)(w + OFF_B2);
    int*   deg    = (int*)(w + OFF_DEG);
    int*   rowptr = (int*)(w + OFF_ROWPTR);
    int*   cursor = (int*)(w + OFF_CURSOR);
    int*   bsums  = (int*)(w + OFF_BSUMS);
    int*   boffs  = (int*)(w + OFF_BOFFS);
    int*   elist  = (int*)(w + OFF_ELIST);

    const int* src = ei;
    const int* dst = ei + EE;

    const int NB1024 = (NN + 1023) / 1024;   // 98

    hipMemsetAsync(deg, 0, NN * sizeof(int), stream);

    stats_kernel<<<GG, 256, 0, stream>>>(x, batch, n1w, n1b, n1ms, A1, B1);

    deg_kernel<<<(EE + 255) / 256, 256, 0, stream>>>(dst, deg);
    scan1<<<NB1024, 256, 0, stream>>>(deg, bsums);
    scan2<<<1, 128, 0, stream>>>(bsums, boffs, NB1024);
    scan3<<<NB1024, 256, 0, stream>>>(deg, boffs, rowptr);
    cursor_copy<<<(NN + 255) / 256, 256, 0, stream>>>(rowptr, cursor);
    fill_kernel<<<(EE + 255) / 256, 256, 0, stream>>>(src, dst, cursor, elist);

    agg_kernel<<<NN, 128, 0, stream>>>(x, batch, A1, B1, rowptr, elist, out);

    gemm_kernel<<<NN / GR, 256, 0, stream>>>(x, batch, A1, B1, wl, bl, wr, out);

    stats_kernel<<<GG, 256, 0, stream>>>(out, batch, n2w, n2b, n2ms, A2, B2);
    apply_kernel<<<(NN * 32 + 255) / 256, 256, 0, stream>>>(out, batch, A2, B2);
}

// Round 2
// 405.802 us; speedup vs baseline: 1.1565x; 1.1565x over previous
//
#include <hip/hip_runtime.h>
#include <math.h>

#define NN 100000
#define EE 600000
#define DD 128
#define GG 256
#define EPSV 1e-5f

typedef __attribute__((ext_vector_type(8))) __bf16 bf16x8;
typedef __attribute__((ext_vector_type(16))) float f32x16;
typedef __attribute__((ext_vector_type(4))) unsigned short us4;

// ---------------- workspace layout (bytes) ----------------
#define OFF_A1      0
#define OFF_B1      131072
#define OFF_A2      262144
#define OFF_B2      393216
#define OFF_DEG     524288      // N ints
#define OFF_ROWPTR  924288      // N+1 ints
#define OFF_CURSOR  1324352     // N ints
#define OFF_BSUMS   1724352     // <=512 ints
#define OFF_BOFFS   1726400     // <=512 ints
#define OFF_ELIST   1728448     // E ints  -> ends at 4,128,448
#define OFF_H1      4128768     // N*D floats (optional, needs big ws)
#define WS_NEED     (OFF_H1 + (size_t)NN * DD * 4)   // 55,328,768

__device__ __forceinline__ int lower_bound_i(const int* __restrict__ a, int n, int v) {
    int lo = 0, hi = n;
    while (lo < hi) { int mid = (lo + hi) >> 1; if (a[mid] < v) lo = mid + 1; else hi = mid; }
    return lo;
}

__device__ __forceinline__ unsigned short f2bf(float f) {
    unsigned int u = __float_as_uint(f);
    unsigned int r = u + 0x7fffu + ((u >> 16) & 1u);
    return (unsigned short)(r >> 16);
}

// ---------------- per-graph stats -> affine (h = A*x + B) ----------------
__global__ __launch_bounds__(256) void stats_kernel(
    const float* __restrict__ X, const int* __restrict__ batch,
    const float* __restrict__ w, const float* __restrict__ bb, const float* __restrict__ ms,
    float* __restrict__ A, float* __restrict__ B)
{
    int g = blockIdx.x;
    __shared__ int rng[2];
    if (threadIdx.x == 0) { rng[0] = lower_bound_i(batch, NN, g); rng[1] = lower_bound_i(batch, NN, g + 1); }
    __syncthreads();
    int start = rng[0], cnt = rng[1] - rng[0];

    const float4* X4 = (const float4*)X;
    float s[4] = {0.f, 0.f, 0.f, 0.f}, q[4] = {0.f, 0.f, 0.f, 0.f};
    int base = start * 32, total = cnt * 32;
    for (int off = threadIdx.x; off < total; off += 256) {
        float4 v = X4[base + off];
        s[0] += v.x; s[1] += v.y; s[2] += v.z; s[3] += v.w;
        q[0] += v.x * v.x; q[1] += v.y * v.y; q[2] += v.z * v.z; q[3] += v.w * v.w;
    }
    __shared__ float ls[256 * 4];
    __shared__ float lq[256 * 4];
    #pragma unroll
    for (int k = 0; k < 4; k++) { ls[threadIdx.x * 4 + k] = s[k]; lq[threadIdx.x * 4 + k] = q[k]; }
    __syncthreads();
    if (threadIdx.x < 32) {
        for (int j = 1; j < 8; j++) {
            int o = (threadIdx.x + 32 * j) * 4;
            #pragma unroll
            for (int k = 0; k < 4; k++) { s[k] += ls[o + k]; q[k] += lq[o + k]; }
        }
        float c = (float)(cnt > 0 ? cnt : 1);
        float inv_c = 1.0f / c;
        #pragma unroll
        for (int k = 0; k < 4; k++) {
            int d = threadIdx.x * 4 + k;
            float m  = s[k] * inv_c;
            float qm = q[k] * inv_c;
            float sc = ms[d];
            float var = qm - m * m * sc * (2.0f - sc);
            float inv = rsqrtf(var + EPSV);
            float Ad = w[d] * inv;
            A[g * DD + d] = Ad;
            B[g * DD + d] = bb[d] - Ad * m * sc;
        }
    }
}

// ---------------- h1 = A1*x + B1 materialization (big-ws path) ----------------
__global__ __launch_bounds__(256) void h1_kernel(
    const float* __restrict__ X, const int* __restrict__ batch,
    const float* __restrict__ A1, const float* __restrict__ B1, float* __restrict__ h1)
{
    int f = blockIdx.x * 256 + threadIdx.x;
    if (f >= NN * 32) return;
    int i = f >> 5, c = f & 31;
    int g = batch[i];
    float4 v = ((const float4*)X)[f];
    float4 a = ((const float4*)A1)[g * 32 + c];
    float4 b = ((const float4*)B1)[g * 32 + c];
    v.x = fmaf(a.x, v.x, b.x); v.y = fmaf(a.y, v.y, b.y);
    v.z = fmaf(a.z, v.z, b.z); v.w = fmaf(a.w, v.w, b.w);
    ((float4*)h1)[f] = v;
}

// ---------------- CSR build ----------------
__global__ __launch_bounds__(256) void deg_kernel(const int* __restrict__ dst, int* __restrict__ deg) {
    int e = blockIdx.x * 256 + threadIdx.x;
    if (e < EE) atomicAdd(&deg[dst[e]], 1);
}

__global__ __launch_bounds__(256) void scan1(const int* __restrict__ deg, int* __restrict__ bsums) {
    int b = blockIdx.x, t = threadIdx.x;
    int base = b * 1024 + t * 4;
    int v = 0;
    #pragma unroll
    for (int k = 0; k < 4; k++) { int i = base + k; if (i < NN) v += deg[i]; }
    __shared__ int sd[256];
    sd[t] = v; __syncthreads();
    for (int off = 128; off > 0; off >>= 1) { if (t < off) sd[t] += sd[t + off]; __syncthreads(); }
    if (t == 0) bsums[b] = sd[0];
}

__global__ __launch_bounds__(128) void scan2(const int* __restrict__ bsums, int* __restrict__ boffs, int nb) {
    int t = threadIdx.x;
    int v = (t < nb) ? bsums[t] : 0;
    __shared__ int sd[128];
    sd[t] = v; __syncthreads();
    for (int off = 1; off < 128; off <<= 1) {
        int a = (t >= off) ? sd[t - off] : 0;
        __syncthreads();
        sd[t] += a;
        __syncthreads();
    }
    if (t < nb) boffs[t] = sd[t] - v;
}

__global__ __launch_bounds__(256) void scan3(const int* __restrict__ deg, const int* __restrict__ boffs,
                                             int* __restrict__ rowptr) {
    int b = blockIdx.x, t = threadIdx.x;
    int base = b * 1024 + t * 4;
    int d0 = 0, d1 = 0, d2 = 0, d3 = 0;
    if (base     < NN) d0 = deg[base];
    if (base + 1 < NN) d1 = deg[base + 1];
    if (base + 2 < NN) d2 = deg[base + 2];
    if (base + 3 < NN) d3 = deg[base + 3];
    int tsum = d0 + d1 + d2 + d3;
    __shared__ int sd[256];
    sd[t] = tsum; __syncthreads();
    for (int off = 1; off < 256; off <<= 1) {
        int a = (t >= off) ? sd[t - off] : 0;
        __syncthreads();
        sd[t] += a;
        __syncthreads();
    }
    int exc = sd[t] - tsum + boffs[b];
    if (base     < NN) rowptr[base]     = exc;
    if (base + 1 < NN) rowptr[base + 1] = exc + d0;
    if (base + 2 < NN) rowptr[base + 2] = exc + d0 + d1;
    if (base + 3 < NN) rowptr[base + 3] = exc + d0 + d1 + d2;
    if (b == 0 && t == 0) rowptr[NN] = EE;
}

__global__ __launch_bounds__(256) void cursor_copy(const int* __restrict__ rowptr, int* __restrict__ cursor) {
    int i = blockIdx.x * 256 + threadIdx.x;
    if (i < NN) cursor[i] = rowptr[i];
}

__global__ __launch_bounds__(256) void fill_kernel(const int* __restrict__ src, const int* __restrict__ dst,
                                                   int* __restrict__ cursor, int* __restrict__ elist) {
    int e = blockIdx.x * 256 + threadIdx.x;
    if (e < EE) {
        int p = atomicAdd(&cursor[dst[e]], 1);
        elist[p] = src[e];
    }
}

// ---------------- gather-max aggregation: 2 nodes per 256-thread block ----------------
__global__ __launch_bounds__(256) void agg_kernel(
    const float* __restrict__ X, const int* __restrict__ batch,
    const float* __restrict__ A1, const float* __restrict__ B1,
    const float* __restrict__ h1,     // may be null (small-ws fallback)
    const int* __restrict__ rowptr, const int* __restrict__ elist, float* __restrict__ H)
{
    int i = blockIdx.x * 2 + (threadIdx.x >> 7);
    int d = threadIdx.x & 127;
    int beg = rowptr[i], end = rowptr[i + 1];
    float acc = -INFINITY;
    if (h1) {
        int e = beg;
        for (; e + 4 <= end; e += 4) {
            int s0 = elist[e], s1 = elist[e + 1], s2 = elist[e + 2], s3 = elist[e + 3];
            float v0 = h1[s0 * DD + d];
            float v1 = h1[s1 * DD + d];
            float v2 = h1[s2 * DD + d];
            float v3 = h1[s3 * DD + d];
            acc = fmaxf(acc, fmaxf(fmaxf(v0, v1), fmaxf(v2, v3)));
        }
        for (; e < end; e++) acc = fmaxf(acc, h1[elist[e] * DD + d]);
    } else {
        int e = beg;
        for (; e + 2 <= end; e += 2) {
            int s0 = elist[e], s1 = elist[e + 1];
            int g0 = batch[s0], g1 = batch[s1];
            float v0 = fmaf(A1[g0 * DD + d], X[s0 * DD + d], B1[g0 * DD + d]);
            float v1 = fmaf(A1[g1 * DD + d], X[s1 * DD + d], B1[g1 * DD + d]);
            acc = fmaxf(acc, fmaxf(v0, v1));
        }
        for (; e < end; e++) {
            int s = elist[e]; int g = batch[s];
            acc = fmaxf(acc, fmaf(A1[g * DD + d], X[s * DD + d], B1[g * DD + d]));
        }
    }
    if (end == beg) acc = 0.f;
    H[i * DD + d] = acc;
}

// ---------------- bf16 MFMA GEMM: h2 = relu(x + [agg|h1] @ [wl;wr]^T + bl) ----------------
// 128 rows x 128 cols per block; 4 waves, each 64x64 via 4x (32x32x16) MFMA tiles.
// BK=64 chunks: k 0..127 = agg (in H) x wl, k 128..255 = h1 x wr.
#define BM 128
#define LDT 72   // ushort stride: 144 B -> 16B aligned, 4-way LDS bank alias only

__global__ __launch_bounds__(256) void gemm_kernel(
    const float* __restrict__ X, const int* __restrict__ batch,
    const float* __restrict__ A1, const float* __restrict__ B1,
    const float* __restrict__ h1,     // may be null
    const float* __restrict__ wl, const float* __restrict__ blv, const float* __restrict__ wr,
    float* __restrict__ H)
{
    __shared__ unsigned short Ut[BM * LDT];
    __shared__ unsigned short Wt[DD * LDT];
    int i0 = blockIdx.x * BM;
    int tid = threadIdx.x;
    int lane = tid & 63, wave = tid >> 6;
    int wrow = (wave >> 1) * 64, wcol = (wave & 1) * 64;
    int m = lane & 31, hf = lane >> 5;

    f32x16 acc00, acc01, acc10, acc11;
    #pragma unroll
    for (int r = 0; r < 16; r++) { acc00[r] = 0.f; acc01[r] = 0.f; acc10[r] = 0.f; acc11[r] = 0.f; }

    for (int c = 0; c < 4; c++) {
        __syncthreads();
        // stage U chunk: 128 rows x 64 k (fp32 -> bf16)
        for (int t = tid; t < BM * 16; t += 256) {
            int r = t >> 4, c4 = t & 15;
            int i = i0 + r; if (i >= NN) i = NN - 1;
            float4 v;
            if (c < 2) {
                v = ((const float4*)H)[i * 32 + c * 16 + c4];
            } else if (h1) {
                v = ((const float4*)h1)[i * 32 + (c - 2) * 16 + c4];
            } else {
                int g = batch[i];
                float4 xv = ((const float4*)X)[i * 32 + (c - 2) * 16 + c4];
                float4 a = ((const float4*)A1)[g * 32 + (c - 2) * 16 + c4];
                float4 b = ((const float4*)B1)[g * 32 + (c - 2) * 16 + c4];
                v.x = fmaf(a.x, xv.x, b.x); v.y = fmaf(a.y, xv.y, b.y);
                v.z = fmaf(a.z, xv.z, b.z); v.w = fmaf(a.w, xv.w, b.w);
            }
            us4 o = { f2bf(v.x), f2bf(v.y), f2bf(v.z), f2bf(v.w) };
            *(us4*)&Ut[r * LDT + c4 * 4] = o;
        }
        // stage W chunk: 128 cols x 64 k
        {
            const float* Wsrc = (c < 2) ? wl : wr;
            int kb = (c & 1) * 16;
            for (int t = tid; t < DD * 16; t += 256) {
                int j = t >> 4, c4 = t & 15;
                float4 v = ((const float4*)Wsrc)[j * 32 + kb + c4];
                us4 o = { f2bf(v.x), f2bf(v.y), f2bf(v.z), f2bf(v.w) };
                *(us4*)&Wt[j * LDT + c4 * 4] = o;
            }
        }
        __syncthreads();
        #pragma unroll
        for (int kk = 0; kk < 4; kk++) {
            int kb2 = kk * 16 + hf * 8;
            bf16x8 a0 = *(const bf16x8*)&Ut[(wrow      + m) * LDT + kb2];
            bf16x8 a1 = *(const bf16x8*)&Ut[(wrow + 32 + m) * LDT + kb2];
            bf16x8 b0 = *(const bf16x8*)&Wt[(wcol      + m) * LDT + kb2];
            bf16x8 b1 = *(const bf16x8*)&Wt[(wcol + 32 + m) * LDT + kb2];
            acc00 = __builtin_amdgcn_mfma_f32_32x32x16_bf16(a0, b0, acc00, 0, 0, 0);
            acc01 = __builtin_amdgcn_mfma_f32_32x32x16_bf16(a0, b1, acc01, 0, 0, 0);
            acc10 = __builtin_amdgcn_mfma_f32_32x32x16_bf16(a1, b0, acc10, 0, 0, 0);
            acc11 = __builtin_amdgcn_mfma_f32_32x32x16_bf16(a1, b1, acc11, 0, 0, 0);
        }
    }

    // epilogue: C/D layout col=lane&31, row=(reg&3)+8*(reg>>2)+4*(lane>>5)
    int col0 = wcol + m, col1 = wcol + 32 + m;
    float bl0 = blv[col0], bl1 = blv[col1];
    #pragma unroll
    for (int reg = 0; reg < 16; reg++) {
        int rl = (reg & 3) + 8 * (reg >> 2) + 4 * hf;
        int ia = i0 + wrow + rl;
        int ib = i0 + wrow + 32 + rl;
        if (ia < NN) {
            float v0 = X[ia * DD + col0] + bl0 + acc00[reg];
            float v1 = X[ia * DD + col1] + bl1 + acc01[reg];
            H[ia * DD + col0] = v0 > 0.f ? v0 : 0.f;
            H[ia * DD + col1] = v1 > 0.f ? v1 : 0.f;
        }
        if (ib < NN) {
            float v0 = X[ib * DD + col0] + bl0 + acc10[reg];
            float v1 = X[ib * DD + col1] + bl1 + acc11[reg];
            H[ib * DD + col0] = v0 > 0.f ? v0 : 0.f;
            H[ib * DD + col1] = v1 > 0.f ? v1 : 0.f;
        }
    }
}

// ---------------- final norm apply (in place on d_out) ----------------
__global__ __launch_bounds__(256) void apply_kernel(float* __restrict__ H, const int* __restrict__ batch,
                                                    const float* __restrict__ A2, const float* __restrict__ B2) {
    int f = blockIdx.x * 256 + threadIdx.x;
    if (f >= NN * 32) return;
    int i = f >> 5, c = f & 31;
    int g = batch[i];
    float4 v = ((float4*)H)[f];
    float4 a = ((const float4*)A2)[g * 32 + c];
    float4 b = ((const float4*)B2)[g * 32 + c];
    v.x = fmaf(a.x, v.x, b.x); v.y = fmaf(a.y, v.y, b.y);
    v.z = fmaf(a.z, v.z, b.z); v.w = fmaf(a.w, v.w, b.w);
    ((float4*)H)[f] = v;
}

extern "C" void kernel_launch(void* const* d_in, const int* in_sizes, int n_in,
                              void* d_out, int out_size, void* d_ws, size_t ws_size,
                              hipStream_t stream) {
    const float* x    = (const float*)d_in[0];
    const int*   ei   = (const int*)d_in[1];
    const int*   batch= (const int*)d_in[2];
    const float* n1w  = (const float*)d_in[3];
    const float* n1b  = (const float*)d_in[4];
    const float* n1ms = (const float*)d_in[5];
    const float* n2w  = (const float*)d_in[6];
    const float* n2b  = (const float*)d_in[7];
    const float* n2ms = (const float*)d_in[8];
    const float* wl   = (const float*)d_in[9];
    const float* bl   = (const float*)d_in[10];
    const float* wr   = (const float*)d_in[11];
    float* out = (float*)d_out;

    char* w = (char*)d_ws;
    float* A1     = (float*)(w + OFF_A1);
    float* B1     = (float*)(w + OFF_B1);
    float* A2     = (float*)(w + OFF_A2);
    float* B2     = (float*)(w + OFF_B2);
    int*   deg    = (int*)(w + OFF_DEG);
    int*   rowptr = (int*)(w + OFF_ROWPTR);
    int*   cursor = (int*)(w + OFF_CURSOR);
    int*   bsums  = (int*)(w + OFF_BSUMS);
    int*   boffs  = (int*)(w + OFF_BOFFS);
    int*   elist  = (int*)(w + OFF_ELIST);
    float* h1     = (ws_size >= WS_NEED) ? (float*)(w + OFF_H1) : nullptr;

    const int* src = ei;
    const int* dst = ei + EE;
    const int NB1024 = (NN + 1023) / 1024;

    hipMemsetAsync(deg, 0, NN * sizeof(int), stream);

    stats_kernel<<<GG, 256, 0, stream>>>(x, batch, n1w, n1b, n1ms, A1, B1);
    if (h1) h1_kernel<<<(NN * 32 + 255) / 256, 256, 0, stream>>>(x, batch, A1, B1, h1);

    deg_kernel<<<(EE + 255) / 256, 256, 0, stream>>>(dst, deg);
    scan1<<<NB1024, 256, 0, stream>>>(deg, bsums);
    scan2<<<1, 128, 0, stream>>>(bsums, boffs, NB1024);
    scan3<<<NB1024, 256, 0, stream>>>(deg, boffs, rowptr);
    cursor_copy<<<(NN + 255) / 256, 256, 0, stream>>>(rowptr, cursor);
    fill_kernel<<<(EE + 255) / 256, 256, 0, stream>>>(src, dst, cursor, elist);

    agg_kernel<<<NN / 2, 256, 0, stream>>>(x, batch, A1, B1, h1, rowptr, elist, out);

    gemm_kernel<<<(NN + BM - 1) / BM, 256, 0, stream>>>(x, batch, A1, B1, h1, wl, bl, wr, out);

    stats_kernel<<<GG, 256, 0, stream>>>(out, batch, n2w, n2b, n2ms, A2, B2);
    apply_kernel<<<(NN * 32 + 255) / 256, 256, 0, stream>>>(out, batch, A2, B2);
}

// Round 3
// 349.817 us; speedup vs baseline: 1.3416x; 1.1600x over previous
//
#include <hip/hip_runtime.h>
#include <math.h>

#define NN 100000
#define EE 600000
#define DD 128
#define GG 256
#define EPSV 1e-5f

typedef __attribute__((ext_vector_type(8))) __bf16 bf16x8;
typedef __attribute__((ext_vector_type(16))) float f32x16;
typedef __attribute__((ext_vector_type(4))) unsigned short us4;

// ---------------- workspace layout (bytes) ----------------
#define OFF_A1      0
#define OFF_B1      131072
#define OFF_A2      262144
#define OFF_B2      393216
#define OFF_DEG     524288      // N ints
#define OFF_ROWPTR  924288      // N+1 ints
#define OFF_CURSOR  1324352     // N ints
#define OFF_BSUMS   1724352     // <=512 ints
#define OFF_BOFFS   1726400     // <=512 ints
#define OFF_ELIST   1728448     // E ints  -> ends 4,128,448
#define OFF_WB      4128448     // 128*256 bf16 = 65536 -> ends 4,193,984
#define OFF_H1B     4193984     // N*128 bf16 = 25,600,000 -> ends 29,793,984
#define WS_NEED_A   29793984ULL

__device__ __forceinline__ int lower_bound_i(const int* __restrict__ a, int n, int v) {
    int lo = 0, hi = n;
    while (lo < hi) { int mid = (lo + hi) >> 1; if (a[mid] < v) lo = mid + 1; else hi = mid; }
    return lo;
}

__device__ __forceinline__ unsigned short f2bf(float f) {
    unsigned int u = __float_as_uint(f);
    unsigned int r = u + 0x7fffu + ((u >> 16) & 1u);
    return (unsigned short)(r >> 16);
}

// ---------------- per-graph stats -> affine (h = A*x + B) ----------------
__global__ __launch_bounds__(256) void stats_kernel(
    const float* __restrict__ X, const int* __restrict__ batch,
    const float* __restrict__ w, const float* __restrict__ bb, const float* __restrict__ ms,
    float* __restrict__ A, float* __restrict__ B)
{
    int g = blockIdx.x;
    __shared__ int rng[2];
    if (threadIdx.x == 0) { rng[0] = lower_bound_i(batch, NN, g); rng[1] = lower_bound_i(batch, NN, g + 1); }
    __syncthreads();
    int start = rng[0], cnt = rng[1] - rng[0];

    const float4* X4 = (const float4*)X;
    float s[4] = {0.f, 0.f, 0.f, 0.f}, q[4] = {0.f, 0.f, 0.f, 0.f};
    int base = start * 32, total = cnt * 32;
    for (int off = threadIdx.x; off < total; off += 256) {
        float4 v = X4[base + off];
        s[0] += v.x; s[1] += v.y; s[2] += v.z; s[3] += v.w;
        q[0] += v.x * v.x; q[1] += v.y * v.y; q[2] += v.z * v.z; q[3] += v.w * v.w;
    }
    __shared__ float ls[256 * 4];
    __shared__ float lq[256 * 4];
    #pragma unroll
    for (int k = 0; k < 4; k++) { ls[threadIdx.x * 4 + k] = s[k]; lq[threadIdx.x * 4 + k] = q[k]; }
    __syncthreads();
    if (threadIdx.x < 32) {
        for (int j = 1; j < 8; j++) {
            int o = (threadIdx.x + 32 * j) * 4;
            #pragma unroll
            for (int k = 0; k < 4; k++) { s[k] += ls[o + k]; q[k] += lq[o + k]; }
        }
        float c = (float)(cnt > 0 ? cnt : 1);
        float inv_c = 1.0f / c;
        #pragma unroll
        for (int k = 0; k < 4; k++) {
            int d = threadIdx.x * 4 + k;
            float m  = s[k] * inv_c;
            float qm = q[k] * inv_c;
            float sc = ms[d];
            float var = qm - m * m * sc * (2.0f - sc);
            float inv = rsqrtf(var + EPSV);
            float Ad = w[d] * inv;
            A[g * DD + d] = Ad;
            B[g * DD + d] = bb[d] - Ad * m * sc;
        }
    }
}

// ---------------- prep: h1 (bf16) + combined weights (bf16) ----------------
// blocks 0..12499: h1b; blocks 12500..12531: wb[j][k] (k<128: wl, else wr)
#define H1_BLOCKS 12500
__global__ __launch_bounds__(256) void prep_kernel(
    const float* __restrict__ X, const int* __restrict__ batch,
    const float* __restrict__ A1, const float* __restrict__ B1,
    const float* __restrict__ wl, const float* __restrict__ wr,
    unsigned short* __restrict__ h1b, unsigned short* __restrict__ wb)
{
    int b = blockIdx.x;
    if (b < H1_BLOCKS) {
        int f = b * 256 + threadIdx.x;          // float4 index over X
        int i = f >> 5, c = f & 31;
        int g = batch[i];
        float4 v = ((const float4*)X)[f];
        float4 a = ((const float4*)A1)[g * 32 + c];
        float4 bb = ((const float4*)B1)[g * 32 + c];
        us4 o = { f2bf(fmaf(a.x, v.x, bb.x)), f2bf(fmaf(a.y, v.y, bb.y)),
                  f2bf(fmaf(a.z, v.z, bb.z)), f2bf(fmaf(a.w, v.w, bb.w)) };
        *(us4*)&h1b[i * DD + c * 4] = o;
    } else {
        int t = (b - H1_BLOCKS) * 256 + threadIdx.x;   // 8192 float4s: j in [0,128), k4 in [0,64)
        if (t >= DD * 64) return;
        int j = t >> 6, k4 = t & 63;
        float4 v = (k4 < 32) ? ((const float4*)wl)[j * 32 + k4]
                             : ((const float4*)wr)[j * 32 + (k4 - 32)];
        us4 o = { f2bf(v.x), f2bf(v.y), f2bf(v.z), f2bf(v.w) };
        *(us4*)&wb[j * 256 + k4 * 4] = o;
    }
}

// ---------------- CSR build ----------------
__global__ __launch_bounds__(256) void deg_kernel(const int* __restrict__ dst, int* __restrict__ deg) {
    int e = blockIdx.x * 256 + threadIdx.x;
    if (e < EE) atomicAdd(&deg[dst[e]], 1);
}

__global__ __launch_bounds__(256) void scan1(const int* __restrict__ deg, int* __restrict__ bsums) {
    int b = blockIdx.x, t = threadIdx.x;
    int base = b * 1024 + t * 4;
    int v = 0;
    #pragma unroll
    for (int k = 0; k < 4; k++) { int i = base + k; if (i < NN) v += deg[i]; }
    __shared__ int sd[256];
    sd[t] = v; __syncthreads();
    for (int off = 128; off > 0; off >>= 1) { if (t < off) sd[t] += sd[t + off]; __syncthreads(); }
    if (t == 0) bsums[b] = sd[0];
}

__global__ __launch_bounds__(128) void scan2(const int* __restrict__ bsums, int* __restrict__ boffs, int nb) {
    int t = threadIdx.x;
    int v = (t < nb) ? bsums[t] : 0;
    __shared__ int sd[128];
    sd[t] = v; __syncthreads();
    for (int off = 1; off < 128; off <<= 1) {
        int a = (t >= off) ? sd[t - off] : 0;
        __syncthreads();
        sd[t] += a;
        __syncthreads();
    }
    if (t < nb) boffs[t] = sd[t] - v;
}

__global__ __launch_bounds__(256) void scan3(const int* __restrict__ deg, const int* __restrict__ boffs,
                                             int* __restrict__ rowptr, int* __restrict__ cursor) {
    int b = blockIdx.x, t = threadIdx.x;
    int base = b * 1024 + t * 4;
    int d0 = 0, d1 = 0, d2 = 0, d3 = 0;
    if (base     < NN) d0 = deg[base];
    if (base + 1 < NN) d1 = deg[base + 1];
    if (base + 2 < NN) d2 = deg[base + 2];
    if (base + 3 < NN) d3 = deg[base + 3];
    int tsum = d0 + d1 + d2 + d3;
    __shared__ int sd[256];
    sd[t] = tsum; __syncthreads();
    for (int off = 1; off < 256; off <<= 1) {
        int a = (t >= off) ? sd[t - off] : 0;
        __syncthreads();
        sd[t] += a;
        __syncthreads();
    }
    int exc = sd[t] - tsum + boffs[b];
    int p0 = exc, p1 = exc + d0, p2 = exc + d0 + d1, p3 = exc + d0 + d1 + d2;
    if (base     < NN) { rowptr[base]     = p0; cursor[base]     = p0; }
    if (base + 1 < NN) { rowptr[base + 1] = p1; cursor[base + 1] = p1; }
    if (base + 2 < NN) { rowptr[base + 2] = p2; cursor[base + 2] = p2; }
    if (base + 3 < NN) { rowptr[base + 3] = p3; cursor[base + 3] = p3; }
    if (b == 0 && t == 0) rowptr[NN] = EE;
}

__global__ __launch_bounds__(256) void fill_kernel(const int* __restrict__ src, const int* __restrict__ dst,
                                                   int* __restrict__ cursor, int* __restrict__ elist) {
    int e = blockIdx.x * 256 + threadIdx.x;
    if (e < EE) {
        int p = atomicAdd(&cursor[dst[e]], 1);
        elist[p] = src[e];
    }
}

// ---------------- agg (path A): wave per node, gather bf16 h1 rows, max ----------------
// writes bf16 agg row i into d_out at byte offset i*512 (first 256 B of the h2 slot)
__global__ __launch_bounds__(256) void agg_a(
    const unsigned short* __restrict__ h1b,
    const int* __restrict__ rowptr, const int* __restrict__ elist, float* __restrict__ out)
{
    int i = blockIdx.x * 4 + (threadIdx.x >> 6);
    if (i >= NN) return;
    int lane = threadIdx.x & 63;
    int beg = rowptr[i], end = rowptr[i + 1];
    float lo = -INFINITY, hi = -INFINITY;
    int e = beg;
    for (; e + 4 <= end; e += 4) {
        int s0 = elist[e], s1 = elist[e + 1], s2 = elist[e + 2], s3 = elist[e + 3];
        unsigned int p0 = *(const unsigned int*)(h1b + s0 * DD + lane * 2);
        unsigned int p1 = *(const unsigned int*)(h1b + s1 * DD + lane * 2);
        unsigned int p2 = *(const unsigned int*)(h1b + s2 * DD + lane * 2);
        unsigned int p3 = *(const unsigned int*)(h1b + s3 * DD + lane * 2);
        float l0 = __uint_as_float(p0 << 16), h0 = __uint_as_float(p0 & 0xffff0000u);
        float l1 = __uint_as_float(p1 << 16), h1v = __uint_as_float(p1 & 0xffff0000u);
        float l2 = __uint_as_float(p2 << 16), h2 = __uint_as_float(p2 & 0xffff0000u);
        float l3 = __uint_as_float(p3 << 16), h3 = __uint_as_float(p3 & 0xffff0000u);
        lo = fmaxf(lo, fmaxf(fmaxf(l0, l1), fmaxf(l2, l3)));
        hi = fmaxf(hi, fmaxf(fmaxf(h0, h1v), fmaxf(h2, h3)));
    }
    for (; e < end; e++) {
        unsigned int p = *(const unsigned int*)(h1b + elist[e] * DD + lane * 2);
        lo = fmaxf(lo, __uint_as_float(p << 16));
        hi = fmaxf(hi, __uint_as_float(p & 0xffff0000u));
    }
    unsigned int r = 0u;
    if (end > beg) r = (__float_as_uint(hi) & 0xffff0000u) | (__float_as_uint(lo) >> 16);
    *(unsigned int*)((char*)out + (size_t)i * 512 + lane * 4) = r;
}

// ---------------- gemm (path A): zero-LDS, wave-per-32-rows, fragments from global ----------------
// h2 = relu(x + agg@wl^T + bl + h1@wr^T); agg read from d_out slots, h2 written over them.
__global__ __launch_bounds__(256) void gemm_a(
    const float* __restrict__ X, const unsigned short* __restrict__ h1b,
    const unsigned short* __restrict__ wb, const float* __restrict__ blv,
    float* __restrict__ out)
{
    int wid = (blockIdx.x * 256 + threadIdx.x) >> 6;
    int i0 = wid * 32;
    if (i0 >= NN) return;
    int lane = threadIdx.x & 63;
    int m = lane & 31, hf = lane >> 5;
    int row = i0 + m;

    const unsigned short* arow_agg = (const unsigned short*)((const char*)out + (size_t)row * 512) + hf * 8;
    const unsigned short* arow_h1  = h1b + row * DD + hf * 8;
    const unsigned short* bcol     = wb + m * 256 + hf * 8;

    f32x16 acc[4];
    #pragma unroll
    for (int c = 0; c < 4; c++)
        #pragma unroll
        for (int r = 0; r < 16; r++) acc[c][r] = 0.f;

    #pragma unroll
    for (int t = 0; t < 8; t++) {                     // k = t*16 + hf*8  (agg x wl)
        bf16x8 a = *(const bf16x8*)(arow_agg + t * 16);
        #pragma unroll
        for (int c = 0; c < 4; c++) {
            bf16x8 b = *(const bf16x8*)(bcol + c * 32 * 256 + t * 16);
            acc[c] = __builtin_amdgcn_mfma_f32_32x32x16_bf16(a, b, acc[c], 0, 0, 0);
        }
    }
    #pragma unroll
    for (int t = 0; t < 8; t++) {                     // k = 128 + t*16 + hf*8  (h1 x wr)
        bf16x8 a = *(const bf16x8*)(arow_h1 + t * 16);
        #pragma unroll
        for (int c = 0; c < 4; c++) {
            bf16x8 b = *(const bf16x8*)(bcol + c * 32 * 256 + 128 + t * 16);
            acc[c] = __builtin_amdgcn_mfma_f32_32x32x16_bf16(a, b, acc[c], 0, 0, 0);
        }
    }

    // epilogue: C/D layout col=lane&31, row=(reg&3)+8*(reg>>2)+4*hf
    float blr[4];
    #pragma unroll
    for (int c = 0; c < 4; c++) blr[c] = blv[c * 32 + m];
    #pragma unroll
    for (int c = 0; c < 4; c++) {
        int col = c * 32 + m;
        #pragma unroll
        for (int reg = 0; reg < 16; reg++) {
            int rl = (reg & 3) + 8 * (reg >> 2) + 4 * hf;
            int i = i0 + rl;
            float v = X[i * DD + col] + blr[c] + acc[c][reg];
            out[i * DD + col] = v > 0.f ? v : 0.f;
        }
    }
}

// ---------------- fallback path B (round-2 validated): fp32 agg + LDS gemm ----------------
__global__ __launch_bounds__(256) void agg_b(
    const float* __restrict__ X, const int* __restrict__ batch,
    const float* __restrict__ A1, const float* __restrict__ B1,
    const int* __restrict__ rowptr, const int* __restrict__ elist, float* __restrict__ H)
{
    int i = blockIdx.x * 2 + (threadIdx.x >> 7);
    int d = threadIdx.x & 127;
    int beg = rowptr[i], end = rowptr[i + 1];
    float acc = -INFINITY;
    int e = beg;
    for (; e + 2 <= end; e += 2) {
        int s0 = elist[e], s1 = elist[e + 1];
        int g0 = batch[s0], g1 = batch[s1];
        float v0 = fmaf(A1[g0 * DD + d], X[s0 * DD + d], B1[g0 * DD + d]);
        float v1 = fmaf(A1[g1 * DD + d], X[s1 * DD + d], B1[g1 * DD + d]);
        acc = fmaxf(acc, fmaxf(v0, v1));
    }
    for (; e < end; e++) {
        int s = elist[e]; int g = batch[s];
        acc = fmaxf(acc, fmaf(A1[g * DD + d], X[s * DD + d], B1[g * DD + d]));
    }
    if (end == beg) acc = 0.f;
    H[i * DD + d] = acc;
}

#define BM 128
#define LDT 72
__global__ __launch_bounds__(256) void gemm_b(
    const float* __restrict__ X, const int* __restrict__ batch,
    const float* __restrict__ A1, const float* __restrict__ B1,
    const float* __restrict__ wl, const float* __restrict__ blv, const float* __restrict__ wr,
    float* __restrict__ H)
{
    __shared__ unsigned short Ut[BM * LDT];
    __shared__ unsigned short Wt[DD * LDT];
    int i0 = blockIdx.x * BM;
    int tid = threadIdx.x;
    int lane = tid & 63, wave = tid >> 6;
    int wrow = (wave >> 1) * 64, wcol = (wave & 1) * 64;
    int m = lane & 31, hf = lane >> 5;

    f32x16 acc00, acc01, acc10, acc11;
    #pragma unroll
    for (int r = 0; r < 16; r++) { acc00[r] = 0.f; acc01[r] = 0.f; acc10[r] = 0.f; acc11[r] = 0.f; }

    for (int c = 0; c < 4; c++) {
        __syncthreads();
        for (int t = tid; t < BM * 16; t += 256) {
            int r = t >> 4, c4 = t & 15;
            int i = i0 + r; if (i >= NN) i = NN - 1;
            float4 v;
            if (c < 2) {
                v = ((const float4*)H)[i * 32 + c * 16 + c4];
            } else {
                int g = batch[i];
                float4 xv = ((const float4*)X)[i * 32 + (c - 2) * 16 + c4];
                float4 a = ((const float4*)A1)[g * 32 + (c - 2) * 16 + c4];
                float4 b = ((const float4*)B1)[g * 32 + (c - 2) * 16 + c4];
                v.x = fmaf(a.x, xv.x, b.x); v.y = fmaf(a.y, xv.y, b.y);
                v.z = fmaf(a.z, xv.z, b.z); v.w = fmaf(a.w, xv.w, b.w);
            }
            us4 o = { f2bf(v.x), f2bf(v.y), f2bf(v.z), f2bf(v.w) };
            *(us4*)&Ut[r * LDT + c4 * 4] = o;
        }
        {
            const float* Wsrc = (c < 2) ? wl : wr;
            int kb = (c & 1) * 16;
            for (int t = tid; t < DD * 16; t += 256) {
                int j = t >> 4, c4 = t & 15;
                float4 v = ((const float4*)Wsrc)[j * 32 + kb + c4];
                us4 o = { f2bf(v.x), f2bf(v.y), f2bf(v.z), f2bf(v.w) };
                *(us4*)&Wt[j * LDT + c4 * 4] = o;
            }
        }
        __syncthreads();
        #pragma unroll
        for (int kk = 0; kk < 4; kk++) {
            int kb2 = kk * 16 + hf * 8;
            bf16x8 a0 = *(const bf16x8*)&Ut[(wrow      + m) * LDT + kb2];
            bf16x8 a1 = *(const bf16x8*)&Ut[(wrow + 32 + m) * LDT + kb2];
            bf16x8 b0 = *(const bf16x8*)&Wt[(wcol      + m) * LDT + kb2];
            bf16x8 b1 = *(const bf16x8*)&Wt[(wcol + 32 + m) * LDT + kb2];
            acc00 = __builtin_amdgcn_mfma_f32_32x32x16_bf16(a0, b0, acc00, 0, 0, 0);
            acc01 = __builtin_amdgcn_mfma_f32_32x32x16_bf16(a0, b1, acc01, 0, 0, 0);
            acc10 = __builtin_amdgcn_mfma_f32_32x32x16_bf16(a1, b0, acc10, 0, 0, 0);
            acc11 = __builtin_amdgcn_mfma_f32_32x32x16_bf16(a1, b1, acc11, 0, 0, 0);
        }
    }

    int col0 = wcol + m, col1 = wcol + 32 + m;
    float bl0 = blv[col0], bl1 = blv[col1];
    #pragma unroll
    for (int reg = 0; reg < 16; reg++) {
        int rl = (reg & 3) + 8 * (reg >> 2) + 4 * hf;
        int ia = i0 + wrow + rl;
        int ib = i0 + wrow + 32 + rl;
        if (ia < NN) {
            float v0 = X[ia * DD + col0] + bl0 + acc00[reg];
            float v1 = X[ia * DD + col1] + bl1 + acc01[reg];
            H[ia * DD + col0] = v0 > 0.f ? v0 : 0.f;
            H[ia * DD + col1] = v1 > 0.f ? v1 : 0.f;
        }
        if (ib < NN) {
            float v0 = X[ib * DD + col0] + bl0 + acc10[reg];
            float v1 = X[ib * DD + col1] + bl1 + acc11[reg];
            H[ib * DD + col0] = v0 > 0.f ? v0 : 0.f;
            H[ib * DD + col1] = v1 > 0.f ? v1 : 0.f;
        }
    }
}

// ---------------- final norm apply (in place on d_out) ----------------
__global__ __launch_bounds__(256) void apply_kernel(float* __restrict__ H, const int* __restrict__ batch,
                                                    const float* __restrict__ A2, const float* __restrict__ B2) {
    int f = blockIdx.x * 256 + threadIdx.x;
    if (f >= NN * 32) return;
    int i = f >> 5, c = f & 31;
    int g = batch[i];
    float4 v = ((float4*)H)[f];
    float4 a = ((const float4*)A2)[g * 32 + c];
    float4 b = ((const float4*)B2)[g * 32 + c];
    v.x = fmaf(a.x, v.x, b.x); v.y = fmaf(a.y, v.y, b.y);
    v.z = fmaf(a.z, v.z, b.z); v.w = fmaf(a.w, v.w, b.w);
    ((float4*)H)[f] = v;
}

extern "C" void kernel_launch(void* const* d_in, const int* in_sizes, int n_in,
                              void* d_out, int out_size, void* d_ws, size_t ws_size,
                              hipStream_t stream) {
    const float* x    = (const float*)d_in[0];
    const int*   ei   = (const int*)d_in[1];
    const int*   batch= (const int*)d_in[2];
    const float* n1w  = (const float*)d_in[3];
    const float* n1b  = (const float*)d_in[4];
    const float* n1ms = (const float*)d_in[5];
    const float* n2w  = (const float*)d_in[6];
    const float* n2b  = (const float*)d_in[7];
    const float* n2ms = (const float*)d_in[8];
    const float* wl   = (const float*)d_in[9];
    const float* bl   = (const float*)d_in[10];
    const float* wr   = (const float*)d_in[11];
    float* out = (float*)d_out;

    char* w = (char*)d_ws;
    float* A1     = (float*)(w + OFF_A1);
    float* B1     = (float*)(w + OFF_B1);
    float* A2     = (float*)(w + OFF_A2);
    float* B2     = (float*)(w + OFF_B2);
    int*   deg    = (int*)(w + OFF_DEG);
    int*   rowptr = (int*)(w + OFF_ROWPTR);
    int*   cursor = (int*)(w + OFF_CURSOR);
    int*   bsums  = (int*)(w + OFF_BSUMS);
    int*   boffs  = (int*)(w + OFF_BOFFS);
    int*   elist  = (int*)(w + OFF_ELIST);
    unsigned short* wb  = (unsigned short*)(w + OFF_WB);
    unsigned short* h1b = (unsigned short*)(w + OFF_H1B);

    const int* src = ei;
    const int* dst = ei + EE;
    const int NB1024 = (NN + 1023) / 1024;
    bool bigws = (ws_size >= WS_NEED_A);

    hipMemsetAsync(deg, 0, NN * sizeof(int), stream);

    stats_kernel<<<GG, 256, 0, stream>>>(x, batch, n1w, n1b, n1ms, A1, B1);
    if (bigws)
        prep_kernel<<<H1_BLOCKS + 32, 256, 0, stream>>>(x, batch, A1, B1, wl, wr, h1b, wb);

    deg_kernel<<<(EE + 255) / 256, 256, 0, stream>>>(dst, deg);
    scan1<<<NB1024, 256, 0, stream>>>(deg, bsums);
    scan2<<<1, 128, 0, stream>>>(bsums, boffs, NB1024);
    scan3<<<NB1024, 256, 0, stream>>>(deg, boffs, rowptr, cursor);
    fill_kernel<<<(EE + 255) / 256, 256, 0, stream>>>(src, dst, cursor, elist);

    if (bigws) {
        agg_a<<<(NN + 3) / 4, 256, 0, stream>>>(h1b, rowptr, elist, out);
        gemm_a<<<(NN / 32 + 3) / 4, 256, 0, stream>>>(x, h1b, wb, bl, out);
    } else {
        agg_b<<<NN / 2, 256, 0, stream>>>(x, batch, A1, B1, rowptr, elist, out);
        gemm_b<<<(NN + BM - 1) / BM, 256, 0, stream>>>(x, batch, A1, B1, wl, bl, wr, out);
    }

    stats_kernel<<<GG, 256, 0, stream>>>(out, batch, n2w, n2b, n2ms, A2, B2);
    apply_kernel<<<(NN * 32 + 255) / 256, 256, 0, stream>>>(out, batch, A2, B2);
}

// Round 4
// 324.512 us; speedup vs baseline: 1.4462x; 1.0780x over previous
//
#include <hip/hip_runtime.h>
#include <math.h>

#define NN 100000
#define EE 600000
#define DD 128
#define GG 256
#define EPSV 1e-5f

typedef __attribute__((ext_vector_type(8))) __bf16 bf16x8;
typedef __attribute__((ext_vector_type(16))) float f32x16;
typedef __attribute__((ext_vector_type(4))) unsigned short us4;

// ---------------- workspace layout (bytes) ----------------
#define OFF_A1      0
#define OFF_B1      131072
#define OFF_A2      262144
#define OFF_B2      393216
#define OFF_DEG     524288      // N ints
#define OFF_ROWPTR  924288      // N+1 ints
#define OFF_CURSOR  1324352     // N ints
#define OFF_BSUMS   1724352     // <=512 ints
#define OFF_BOFFS   1726400     // <=512 ints
#define OFF_ELIST   1728448     // E ints  -> ends 4,128,448
#define OFF_H1B     4128448     // N*128 bf16 = 25,600,000
#define WS_NEED_A   (OFF_H1B + 25600000ULL)

__device__ __forceinline__ int lower_bound_i(const int* __restrict__ a, int n, int v) {
    int lo = 0, hi = n;
    while (lo < hi) { int mid = (lo + hi) >> 1; if (a[mid] < v) lo = mid + 1; else hi = mid; }
    return lo;
}

__device__ __forceinline__ unsigned short f2bf(float f) {
    unsigned int u = __float_as_uint(f);
    unsigned int r = u + 0x7fffu + ((u >> 16) & 1u);
    return (unsigned short)(r >> 16);
}

// ---------------- per-graph stats -> affine; optionally writes h1 (bf16) ----------------
// one 512-thread block per graph; batch sorted -> contiguous row range.
__global__ __launch_bounds__(512) void stats_kernel(
    const float* __restrict__ X, const int* __restrict__ batch,
    const float* __restrict__ w, const float* __restrict__ bb, const float* __restrict__ ms,
    float* __restrict__ A, float* __restrict__ B, unsigned short* __restrict__ h1b)
{
    int g = blockIdx.x;
    int t = threadIdx.x;
    __shared__ int rng[2];
    __shared__ float ls[512 * 4];
    __shared__ float lq[512 * 4];
    __shared__ float sA[DD], sB[DD];
    if (t == 0) { rng[0] = lower_bound_i(batch, NN, g); rng[1] = lower_bound_i(batch, NN, g + 1); }
    __syncthreads();
    int start = rng[0], cnt = rng[1] - rng[0];

    const float4* X4 = (const float4*)X;
    float s[4] = {0.f, 0.f, 0.f, 0.f}, q[4] = {0.f, 0.f, 0.f, 0.f};
    int base = start * 32, total = cnt * 32;
    for (int off = t; off < total; off += 512) {
        float4 v = X4[base + off];
        s[0] += v.x; s[1] += v.y; s[2] += v.z; s[3] += v.w;
        q[0] += v.x * v.x; q[1] += v.y * v.y; q[2] += v.z * v.z; q[3] += v.w * v.w;
    }
    #pragma unroll
    for (int k = 0; k < 4; k++) { ls[t * 4 + k] = s[k]; lq[t * 4 + k] = q[k]; }
    __syncthreads();
    if (t < 32) {
        for (int j = 1; j < 16; j++) {
            int o = (t + 32 * j) * 4;
            #pragma unroll
            for (int k = 0; k < 4; k++) { s[k] += ls[o + k]; q[k] += lq[o + k]; }
        }
        float c = (float)(cnt > 0 ? cnt : 1);
        float inv_c = 1.0f / c;
        #pragma unroll
        for (int k = 0; k < 4; k++) {
            int d = t * 4 + k;
            float m  = s[k] * inv_c;
            float qm = q[k] * inv_c;
            float sc = ms[d];
            float var = qm - m * m * sc * (2.0f - sc);
            float inv = rsqrtf(var + EPSV);
            float Ad = w[d] * inv;
            float Bd = bb[d] - Ad * m * sc;
            A[g * DD + d] = Ad;
            B[g * DD + d] = Bd;
            sA[d] = Ad; sB[d] = Bd;
        }
    }
    if (!h1b) return;
    __syncthreads();
    for (int off = t; off < total; off += 512) {
        int f = base + off;
        int i = f >> 5, c4 = f & 31;
        float4 v = X4[f];
        us4 o = { f2bf(fmaf(sA[c4 * 4 + 0], v.x, sB[c4 * 4 + 0])),
                  f2bf(fmaf(sA[c4 * 4 + 1], v.y, sB[c4 * 4 + 1])),
                  f2bf(fmaf(sA[c4 * 4 + 2], v.z, sB[c4 * 4 + 2])),
                  f2bf(fmaf(sA[c4 * 4 + 3], v.w, sB[c4 * 4 + 3])) };
        *(us4*)&h1b[i * DD + c4 * 4] = o;
    }
}

// ---------------- CSR build ----------------
__global__ __launch_bounds__(256) void deg_kernel(const int* __restrict__ dst, int* __restrict__ deg) {
    int e = blockIdx.x * 256 + threadIdx.x;
    if (e < EE) atomicAdd(&deg[dst[e]], 1);
}

__global__ __launch_bounds__(256) void scan1(const int* __restrict__ deg, int* __restrict__ bsums) {
    int b = blockIdx.x, t = threadIdx.x;
    int base = b * 1024 + t * 4;
    int v = 0;
    #pragma unroll
    for (int k = 0; k < 4; k++) { int i = base + k; if (i < NN) v += deg[i]; }
    __shared__ int sd[256];
    sd[t] = v; __syncthreads();
    for (int off = 128; off > 0; off >>= 1) { if (t < off) sd[t] += sd[t + off]; __syncthreads(); }
    if (t == 0) bsums[b] = sd[0];
}

__global__ __launch_bounds__(128) void scan2(const int* __restrict__ bsums, int* __restrict__ boffs, int nb) {
    int t = threadIdx.x;
    int v = (t < nb) ? bsums[t] : 0;
    __shared__ int sd[128];
    sd[t] = v; __syncthreads();
    for (int off = 1; off < 128; off <<= 1) {
        int a = (t >= off) ? sd[t - off] : 0;
        __syncthreads();
        sd[t] += a;
        __syncthreads();
    }
    if (t < nb) boffs[t] = sd[t] - v;
}

__global__ __launch_bounds__(256) void scan3(const int* __restrict__ deg, const int* __restrict__ boffs,
                                             int* __restrict__ rowptr, int* __restrict__ cursor) {
    int b = blockIdx.x, t = threadIdx.x;
    int base = b * 1024 + t * 4;
    int d0 = 0, d1 = 0, d2 = 0, d3 = 0;
    if (base     < NN) d0 = deg[base];
    if (base + 1 < NN) d1 = deg[base + 1];
    if (base + 2 < NN) d2 = deg[base + 2];
    if (base + 3 < NN) d3 = deg[base + 3];
    int tsum = d0 + d1 + d2 + d3;
    __shared__ int sd[256];
    sd[t] = tsum; __syncthreads();
    for (int off = 1; off < 256; off <<= 1) {
        int a = (t >= off) ? sd[t - off] : 0;
        __syncthreads();
        sd[t] += a;
        __syncthreads();
    }
    int exc = sd[t] - tsum + boffs[b];
    int p0 = exc, p1 = exc + d0, p2 = exc + d0 + d1, p3 = exc + d0 + d1 + d2;
    if (base     < NN) { rowptr[base]     = p0; cursor[base]     = p0; }
    if (base + 1 < NN) { rowptr[base + 1] = p1; cursor[base + 1] = p1; }
    if (base + 2 < NN) { rowptr[base + 2] = p2; cursor[base + 2] = p2; }
    if (base + 3 < NN) { rowptr[base + 3] = p3; cursor[base + 3] = p3; }
    if (b == 0 && t == 0) rowptr[NN] = EE;
}

__global__ __launch_bounds__(256) void fill_kernel(const int* __restrict__ src, const int* __restrict__ dst,
                                                   int* __restrict__ cursor, int* __restrict__ elist) {
    int e = blockIdx.x * 256 + threadIdx.x;
    if (e < EE) {
        int p = atomicAdd(&cursor[dst[e]], 1);
        elist[p] = src[e];
    }
}

// ---------------- agg (path A): wave per node, 2 edges per load instr ----------------
// lanes 0-31 own even edge, lanes 32-63 own odd edge; 8B/lane; shfl-combine.
// writes bf16 agg row i into d_out at byte offset i*512.
__global__ __launch_bounds__(256) void agg_a(
    const unsigned short* __restrict__ h1b,
    const int* __restrict__ rowptr, const int* __restrict__ elist, float* __restrict__ out)
{
    int i = blockIdx.x * 4 + (threadIdx.x >> 6);
    if (i >= NN) return;
    int lane = threadIdx.x & 63;
    int half = lane >> 5, j = lane & 31;
    int beg = rowptr[i], end = rowptr[i + 1];
    float a0 = -INFINITY, a1 = -INFINITY, a2 = -INFINITY, a3 = -INFINITY;
    int e = beg;
    for (; e + 4 <= end; e += 4) {
        int s0 = elist[e], s1 = elist[e + 1], s2 = elist[e + 2], s3 = elist[e + 3];
        int rA = half ? s1 : s0;
        int rB = half ? s3 : s2;
        us4 pA = *(const us4*)(h1b + rA * DD + j * 4);
        us4 pB = *(const us4*)(h1b + rB * DD + j * 4);
        a0 = fmaxf(a0, fmaxf(__uint_as_float((unsigned)pA[0] << 16), __uint_as_float((unsigned)pB[0] << 16)));
        a1 = fmaxf(a1, fmaxf(__uint_as_float((unsigned)pA[1] << 16), __uint_as_float((unsigned)pB[1] << 16)));
        a2 = fmaxf(a2, fmaxf(__uint_as_float((unsigned)pA[2] << 16), __uint_as_float((unsigned)pB[2] << 16)));
        a3 = fmaxf(a3, fmaxf(__uint_as_float((unsigned)pA[3] << 16), __uint_as_float((unsigned)pB[3] << 16)));
    }
    for (; e < end; e += 2) {
        int s0 = elist[e];
        int s1 = (e + 1 < end) ? elist[e + 1] : s0;
        int r = half ? s1 : s0;
        us4 p = *(const us4*)(h1b + r * DD + j * 4);
        a0 = fmaxf(a0, __uint_as_float((unsigned)p[0] << 16));
        a1 = fmaxf(a1, __uint_as_float((unsigned)p[1] << 16));
        a2 = fmaxf(a2, __uint_as_float((unsigned)p[2] << 16));
        a3 = fmaxf(a3, __uint_as_float((unsigned)p[3] << 16));
    }
    a0 = fmaxf(a0, __shfl_xor(a0, 32, 64));
    a1 = fmaxf(a1, __shfl_xor(a1, 32, 64));
    a2 = fmaxf(a2, __shfl_xor(a2, 32, 64));
    a3 = fmaxf(a3, __shfl_xor(a3, 32, 64));
    if (half == 0) {
        us4 r = { 0, 0, 0, 0 };
        if (end > beg) {
            r[0] = (unsigned short)(__float_as_uint(a0) >> 16);
            r[1] = (unsigned short)(__float_as_uint(a1) >> 16);
            r[2] = (unsigned short)(__float_as_uint(a2) >> 16);
            r[3] = (unsigned short)(__float_as_uint(a3) >> 16);
        }
        *(us4*)((unsigned short*)((char*)out + (size_t)i * 512) + j * 4) = r;
    }
}

// ---------------- gemm (path A): weights in LDS, wave per 32 rows ----------------
// h2 = relu(x + agg@wl^T + bl + h1@wr^T); agg read from d_out slots, h2 written over them.
#define WSTR 264   // short stride per weight row; 132 dwords = 4 mod 32 (validated conflict-free class)
__global__ __launch_bounds__(512) void gemm_a(
    const float* __restrict__ X, const unsigned short* __restrict__ h1b,
    const float* __restrict__ wl, const float* __restrict__ wr, const float* __restrict__ blv,
    float* __restrict__ out)
{
    __shared__ unsigned short sW[DD * WSTR];   // 67.6 KB
    int tid = threadIdx.x;
    // stage combined weights [col j][k 0..255] (k<128: wl, else wr), fp32 -> bf16
    for (int t = tid; t < DD * 64; t += 512) {
        int j = t >> 6, k4 = t & 63;
        float4 v = (k4 < 32) ? ((const float4*)wl)[j * 32 + k4]
                             : ((const float4*)wr)[j * 32 + (k4 - 32)];
        us4 o = { f2bf(v.x), f2bf(v.y), f2bf(v.z), f2bf(v.w) };
        *(us4*)&sW[j * WSTR + k4 * 4] = o;
    }
    __syncthreads();

    int wid = blockIdx.x * 8 + (tid >> 6);
    int i0 = wid * 32;
    if (i0 >= NN) return;
    int lane = tid & 63;
    int m = lane & 31, hf = lane >> 5;
    int row = i0 + m;

    const unsigned short* arow_agg = (const unsigned short*)((const char*)out + (size_t)row * 512) + hf * 8;
    const unsigned short* arow_h1  = h1b + row * DD + hf * 8;

    f32x16 acc[4];
    #pragma unroll
    for (int c = 0; c < 4; c++)
        #pragma unroll
        for (int r = 0; r < 16; r++) acc[c][r] = 0.f;

    // half 1: agg x wl  (k = s*16 + hf*8, s=0..7)
    {
        bf16x8 af[8];
        #pragma unroll
        for (int s = 0; s < 8; s++) af[s] = *(const bf16x8*)(arow_agg + s * 16);
        #pragma unroll
        for (int s = 0; s < 8; s++) {
            #pragma unroll
            for (int c = 0; c < 4; c++) {
                bf16x8 b = *(const bf16x8*)&sW[(c * 32 + m) * WSTR + s * 16 + hf * 8];
                acc[c] = __builtin_amdgcn_mfma_f32_32x32x16_bf16(af[s], b, acc[c], 0, 0, 0);
            }
        }
    }
    // half 2: h1 x wr  (k = 128 + s*16 + hf*8)
    {
        bf16x8 af[8];
        #pragma unroll
        for (int s = 0; s < 8; s++) af[s] = *(const bf16x8*)(arow_h1 + s * 16);
        #pragma unroll
        for (int s = 0; s < 8; s++) {
            #pragma unroll
            for (int c = 0; c < 4; c++) {
                bf16x8 b = *(const bf16x8*)&sW[(c * 32 + m) * WSTR + 128 + s * 16 + hf * 8];
                acc[c] = __builtin_amdgcn_mfma_f32_32x32x16_bf16(af[s], b, acc[c], 0, 0, 0);
            }
        }
    }

    // epilogue: C/D layout col=lane&31, row=(reg&3)+8*(reg>>2)+4*hf
    float blr[4];
    #pragma unroll
    for (int c = 0; c < 4; c++) blr[c] = blv[c * 32 + m];
    #pragma unroll
    for (int c = 0; c < 4; c++) {
        int col = c * 32 + m;
        #pragma unroll
        for (int reg = 0; reg < 16; reg++) {
            int rl = (reg & 3) + 8 * (reg >> 2) + 4 * hf;
            int i = i0 + rl;
            float v = X[i * DD + col] + blr[c] + acc[c][reg];
            out[i * DD + col] = v > 0.f ? v : 0.f;
        }
    }
}

// ---------------- fallback path B (round-2 validated): fp32 agg + LDS gemm ----------------
__global__ __launch_bounds__(256) void agg_b(
    const float* __restrict__ X, const int* __restrict__ batch,
    const float* __restrict__ A1, const float* __restrict__ B1,
    const int* __restrict__ rowptr, const int* __restrict__ elist, float* __restrict__ H)
{
    int i = blockIdx.x * 2 + (threadIdx.x >> 7);
    int d = threadIdx.x & 127;
    int beg = rowptr[i], end = rowptr[i + 1];
    float acc = -INFINITY;
    int e = beg;
    for (; e + 2 <= end; e += 2) {
        int s0 = elist[e], s1 = elist[e + 1];
        int g0 = batch[s0], g1 = batch[s1];
        float v0 = fmaf(A1[g0 * DD + d], X[s0 * DD + d], B1[g0 * DD + d]);
        float v1 = fmaf(A1[g1 * DD + d], X[s1 * DD + d], B1[g1 * DD + d]);
        acc = fmaxf(acc, fmaxf(v0, v1));
    }
    for (; e < end; e++) {
        int s = elist[e]; int g = batch[s];
        acc = fmaxf(acc, fmaf(A1[g * DD + d], X[s * DD + d], B1[g * DD + d]));
    }
    if (end == beg) acc = 0.f;
    H[i * DD + d] = acc;
}

#define BM 128
#define LDT 72
__global__ __launch_bounds__(256) void gemm_b(
    const float* __restrict__ X, const int* __restrict__ batch,
    const float* __restrict__ A1, const float* __restrict__ B1,
    const float* __restrict__ wl, const float* __restrict__ blv, const float* __restrict__ wr,
    float* __restrict__ H)
{
    __shared__ unsigned short Ut[BM * LDT];
    __shared__ unsigned short Wt[DD * LDT];
    int i0 = blockIdx.x * BM;
    int tid = threadIdx.x;
    int lane = tid & 63, wave = tid >> 6;
    int wrow = (wave >> 1) * 64, wcol = (wave & 1) * 64;
    int m = lane & 31, hf = lane >> 5;

    f32x16 acc00, acc01, acc10, acc11;
    #pragma unroll
    for (int r = 0; r < 16; r++) { acc00[r] = 0.f; acc01[r] = 0.f; acc10[r] = 0.f; acc11[r] = 0.f; }

    for (int c = 0; c < 4; c++) {
        __syncthreads();
        for (int t = tid; t < BM * 16; t += 256) {
            int r = t >> 4, c4 = t & 15;
            int i = i0 + r; if (i >= NN) i = NN - 1;
            float4 v;
            if (c < 2) {
                v = ((const float4*)H)[i * 32 + c * 16 + c4];
            } else {
                int g = batch[i];
                float4 xv = ((const float4*)X)[i * 32 + (c - 2) * 16 + c4];
                float4 a = ((const float4*)A1)[g * 32 + (c - 2) * 16 + c4];
                float4 b = ((const float4*)B1)[g * 32 + (c - 2) * 16 + c4];
                v.x = fmaf(a.x, xv.x, b.x); v.y = fmaf(a.y, xv.y, b.y);
                v.z = fmaf(a.z, xv.z, b.z); v.w = fmaf(a.w, xv.w, b.w);
            }
            us4 o = { f2bf(v.x), f2bf(v.y), f2bf(v.z), f2bf(v.w) };
            *(us4*)&Ut[r * LDT + c4 * 4] = o;
        }
        {
            const float* Wsrc = (c < 2) ? wl : wr;
            int kb = (c & 1) * 16;
            for (int t = tid; t < DD * 16; t += 256) {
                int j = t >> 4, c4 = t & 15;
                float4 v = ((const float4*)Wsrc)[j * 32 + kb + c4];
                us4 o = { f2bf(v.x), f2bf(v.y), f2bf(v.z), f2bf(v.w) };
                *(us4*)&Wt[j * LDT + c4 * 4] = o;
            }
        }
        __syncthreads();
        #pragma unroll
        for (int kk = 0; kk < 4; kk++) {
            int kb2 = kk * 16 + hf * 8;
            bf16x8 a0 = *(const bf16x8*)&Ut[(wrow      + m) * LDT + kb2];
            bf16x8 a1 = *(const bf16x8*)&Ut[(wrow + 32 + m) * LDT + kb2];
            bf16x8 b0 = *(const bf16x8*)&Wt[(wcol      + m) * LDT + kb2];
            bf16x8 b1 = *(const bf16x8*)&Wt[(wcol + 32 + m) * LDT + kb2];
            acc00 = __builtin_amdgcn_mfma_f32_32x32x16_bf16(a0, b0, acc00, 0, 0, 0);
            acc01 = __builtin_amdgcn_mfma_f32_32x32x16_bf16(a0, b1, acc01, 0, 0, 0);
            acc10 = __builtin_amdgcn_mfma_f32_32x32x16_bf16(a1, b0, acc10, 0, 0, 0);
            acc11 = __builtin_amdgcn_mfma_f32_32x32x16_bf16(a1, b1, acc11, 0, 0, 0);
        }
    }

    int col0 = wcol + m, col1 = wcol + 32 + m;
    float bl0 = blv[col0], bl1 = blv[col1];
    #pragma unroll
    for (int reg = 0; reg < 16; reg++) {
        int rl = (reg & 3) + 8 * (reg >> 2) + 4 * hf;
        int ia = i0 + wrow + rl;
        int ib = i0 + wrow + 32 + rl;
        if (ia < NN) {
            float v0 = X[ia * DD + col0] + bl0 + acc00[reg];
            float v1 = X[ia * DD + col1] + bl1 + acc01[reg];
            H[ia * DD + col0] = v0 > 0.f ? v0 : 0.f;
            H[ia * DD + col1] = v1 > 0.f ? v1 : 0.f;
        }
        if (ib < NN) {
            float v0 = X[ib * DD + col0] + bl0 + acc10[reg];
            float v1 = X[ib * DD + col1] + bl1 + acc11[reg];
            H[ib * DD + col0] = v0 > 0.f ? v0 : 0.f;
            H[ib * DD + col1] = v1 > 0.f ? v1 : 0.f;
        }
    }
}

// ---------------- final norm apply (in place on d_out) ----------------
__global__ __launch_bounds__(256) void apply_kernel(float* __restrict__ H, const int* __restrict__ batch,
                                                    const float* __restrict__ A2, const float* __restrict__ B2) {
    int f = blockIdx.x * 256 + threadIdx.x;
    if (f >= NN * 32) return;
    int i = f >> 5, c = f & 31;
    int g = batch[i];
    float4 v = ((float4*)H)[f];
    float4 a = ((const float4*)A2)[g * 32 + c];
    float4 b = ((const float4*)B2)[g * 32 + c];
    v.x = fmaf(a.x, v.x, b.x); v.y = fmaf(a.y, v.y, b.y);
    v.z = fmaf(a.z, v.z, b.z); v.w = fmaf(a.w, v.w, b.w);
    ((float4*)H)[f] = v;
}

extern "C" void kernel_launch(void* const* d_in, const int* in_sizes, int n_in,
                              void* d_out, int out_size, void* d_ws, size_t ws_size,
                              hipStream_t stream) {
    const float* x    = (const float*)d_in[0];
    const int*   ei   = (const int*)d_in[1];
    const int*   batch= (const int*)d_in[2];
    const float* n1w  = (const float*)d_in[3];
    const float* n1b  = (const float*)d_in[4];
    const float* n1ms = (const float*)d_in[5];
    const float* n2w  = (const float*)d_in[6];
    const float* n2b  = (const float*)d_in[7];
    const float* n2ms = (const float*)d_in[8];
    const float* wl   = (const float*)d_in[9];
    const float* bl   = (const float*)d_in[10];
    const float* wr   = (const float*)d_in[11];
    float* out = (float*)d_out;

    char* w = (char*)d_ws;
    float* A1     = (float*)(w + OFF_A1);
    float* B1     = (float*)(w + OFF_B1);
    float* A2     = (float*)(w + OFF_A2);
    float* B2     = (float*)(w + OFF_B2);
    int*   deg    = (int*)(w + OFF_DEG);
    int*   rowptr = (int*)(w + OFF_ROWPTR);
    int*   cursor = (int*)(w + OFF_CURSOR);
    int*   bsums  = (int*)(w + OFF_BSUMS);
    int*   boffs  = (int*)(w + OFF_BOFFS);
    int*   elist  = (int*)(w + OFF_ELIST);
    unsigned short* h1b = (unsigned short*)(w + OFF_H1B);

    const int* src = ei;
    const int* dst = ei + EE;
    const int NB1024 = (NN + 1023) / 1024;
    bool bigws = (ws_size >= WS_NEED_A);

    hipMemsetAsync(deg, 0, NN * sizeof(int), stream);

    stats_kernel<<<GG, 512, 0, stream>>>(x, batch, n1w, n1b, n1ms, A1, B1,
                                         bigws ? h1b : (unsigned short*)nullptr);

    deg_kernel<<<(EE + 255) / 256, 256, 0, stream>>>(dst, deg);
    scan1<<<NB1024, 256, 0, stream>>>(deg, bsums);
    scan2<<<1, 128, 0, stream>>>(bsums, boffs, NB1024);
    scan3<<<NB1024, 256, 0, stream>>>(deg, boffs, rowptr, cursor);
    fill_kernel<<<(EE + 255) / 256, 256, 0, stream>>>(src, dst, cursor, elist);

    if (bigws) {
        agg_a<<<(NN + 3) / 4, 256, 0, stream>>>(h1b, rowptr, elist, out);
        gemm_a<<<(NN / 32 + 7) / 8, 512, 0, stream>>>(x, h1b, wl, wr, bl, out);
    } else {
        agg_b<<<NN / 2, 256, 0, stream>>>(x, batch, A1, B1, rowptr, elist, out);
        gemm_b<<<(NN + BM - 1) / BM, 256, 0, stream>>>(x, batch, A1, B1, wl, bl, wr, out);
    }

    stats_kernel<<<GG, 512, 0, stream>>>(out, batch, n2w, n2b, n2ms, A2, B2,
                                         (unsigned short*)nullptr);
    apply_kernel<<<(NN * 32 + 255) / 256, 256, 0, stream>>>(out, batch, A2, B2);
}

// Round 5
// 322.233 us; speedup vs baseline: 1.4564x; 1.0071x over previous
//
#include <hip/hip_runtime.h>
#include <math.h>

#define NN 100000
#define EE 600000
#define DD 128
#define GG 256
#define EPSV 1e-5f

typedef __attribute__((ext_vector_type(8))) __bf16 bf16x8;
typedef __attribute__((ext_vector_type(16))) float f32x16;
typedef __attribute__((ext_vector_type(4))) unsigned short us4;

// ---------------- workspace layout (bytes) ----------------
#define OFF_A1      0
#define OFF_B1      131072
#define OFF_A2      262144
#define OFF_B2      393216
#define OFF_DEG     524288      // N ints
#define OFF_ROWPTR  924288      // N+1 ints
#define OFF_CURSOR  1324352     // N ints
#define OFF_BSUMS   1724352     // <=512 ints
#define OFF_BOFFS   1726400     // <=512 ints (unused now)
#define OFF_ELIST   1728448     // E ints  -> ends 4,128,448
#define OFF_WB      4128448     // 128*256 bf16 = 65,536 -> ends 4,193,984
#define OFF_H1B     4193984     // N*128 bf16 = 25,600,000
#define WS_NEED_A   (OFF_H1B + 25600000ULL)

__device__ __forceinline__ int lower_bound_i(const int* __restrict__ a, int n, int v) {
    int lo = 0, hi = n;
    while (lo < hi) { int mid = (lo + hi) >> 1; if (a[mid] < v) lo = mid + 1; else hi = mid; }
    return lo;
}

__device__ __forceinline__ unsigned short f2bf(float f) {
    unsigned int u = __float_as_uint(f);
    unsigned int r = u + 0x7fffu + ((u >> 16) & 1u);
    return (unsigned short)(r >> 16);
}

// ---------------- per-graph stats -> affine; mode 1: write h1b bf16 (+wb conv); mode 2: apply in place ----------------
// one 512-thread block per graph (blocks GG..GG+1 in mode 1 convert weights into wb).
__global__ __launch_bounds__(512) void stats_kernel(
    const float* X, const int* __restrict__ batch,
    const float* __restrict__ w, const float* __restrict__ bb, const float* __restrict__ ms,
    float* __restrict__ A, float* __restrict__ B,
    unsigned short* __restrict__ h1b, unsigned short* __restrict__ wb,
    const float* __restrict__ wl, const float* __restrict__ wr, int mode)
{
    int g = blockIdx.x;
    int t = threadIdx.x;
    if (g >= GG) {
        // weight conversion blocks (mode 1 with wb only)
        if (mode == 1 && wb) {
            const float* W = (g == GG) ? wl : wr;
            int kofs = (g == GG) ? 0 : 128;
            for (int tt = t; tt < DD * 32; tt += 512) {
                int j = tt >> 5, k4 = tt & 31;
                float4 v = ((const float4*)W)[j * 32 + k4];
                us4 o = { f2bf(v.x), f2bf(v.y), f2bf(v.z), f2bf(v.w) };
                *(us4*)&wb[j * 256 + kofs + k4 * 4] = o;
            }
        }
        return;
    }
    __shared__ int rng[2];
    __shared__ float ls[512 * 4];
    __shared__ float lq[512 * 4];
    __shared__ float sA[DD], sB[DD];
    if (t == 0) { rng[0] = lower_bound_i(batch, NN, g); rng[1] = lower_bound_i(batch, NN, g + 1); }
    __syncthreads();
    int start = rng[0], cnt = rng[1] - rng[0];

    const float4* X4 = (const float4*)X;
    float s[4] = {0.f, 0.f, 0.f, 0.f}, q[4] = {0.f, 0.f, 0.f, 0.f};
    int base = start * 32, total = cnt * 32;
    for (int off = t; off < total; off += 512) {
        float4 v = X4[base + off];
        s[0] += v.x; s[1] += v.y; s[2] += v.z; s[3] += v.w;
        q[0] += v.x * v.x; q[1] += v.y * v.y; q[2] += v.z * v.z; q[3] += v.w * v.w;
    }
    #pragma unroll
    for (int k = 0; k < 4; k++) { ls[t * 4 + k] = s[k]; lq[t * 4 + k] = q[k]; }
    __syncthreads();
    if (t < 32) {
        for (int j = 1; j < 16; j++) {
            int o = (t + 32 * j) * 4;
            #pragma unroll
            for (int k = 0; k < 4; k++) { s[k] += ls[o + k]; q[k] += lq[o + k]; }
        }
        float c = (float)(cnt > 0 ? cnt : 1);
        float inv_c = 1.0f / c;
        #pragma unroll
        for (int k = 0; k < 4; k++) {
            int d = t * 4 + k;
            float m  = s[k] * inv_c;
            float qm = q[k] * inv_c;
            float sc = ms[d];
            float var = qm - m * m * sc * (2.0f - sc);
            float inv = rsqrtf(var + EPSV);
            float Ad = w[d] * inv;
            float Bd = bb[d] - Ad * m * sc;
            A[g * DD + d] = Ad;
            B[g * DD + d] = Bd;
            sA[d] = Ad; sB[d] = Bd;
        }
    }
    if (mode == 1 && h1b) {
        __syncthreads();
        for (int off = t; off < total; off += 512) {
            int f = base + off;
            int i = f >> 5, c4 = f & 31;
            float4 v = X4[f];
            us4 o = { f2bf(fmaf(sA[c4 * 4 + 0], v.x, sB[c4 * 4 + 0])),
                      f2bf(fmaf(sA[c4 * 4 + 1], v.y, sB[c4 * 4 + 1])),
                      f2bf(fmaf(sA[c4 * 4 + 2], v.z, sB[c4 * 4 + 2])),
                      f2bf(fmaf(sA[c4 * 4 + 3], v.w, sB[c4 * 4 + 3])) };
            *(us4*)&h1b[i * DD + c4 * 4] = o;
        }
    } else if (mode == 2) {
        // apply the norm in place (rows are L2-hot from pass 1)
        __syncthreads();
        float4* Xw = (float4*)X;
        for (int off = t; off < total; off += 512) {
            int f = base + off;
            int c4 = f & 31;
            float4 v = Xw[f];
            v.x = fmaf(sA[c4 * 4 + 0], v.x, sB[c4 * 4 + 0]);
            v.y = fmaf(sA[c4 * 4 + 1], v.y, sB[c4 * 4 + 1]);
            v.z = fmaf(sA[c4 * 4 + 2], v.z, sB[c4 * 4 + 2]);
            v.w = fmaf(sA[c4 * 4 + 3], v.w, sB[c4 * 4 + 3]);
            Xw[f] = v;
        }
    }
}

// ---------------- CSR build ----------------
__global__ __launch_bounds__(256) void deg_kernel(const int* __restrict__ dst, int* __restrict__ deg) {
    int e = blockIdx.x * 256 + threadIdx.x;
    if (e < EE) atomicAdd(&deg[dst[e]], 1);
}

__global__ __launch_bounds__(256) void scan1(const int* __restrict__ deg, int* __restrict__ bsums) {
    int b = blockIdx.x, t = threadIdx.x;
    int base = b * 1024 + t * 4;
    int v = 0;
    #pragma unroll
    for (int k = 0; k < 4; k++) { int i = base + k; if (i < NN) v += deg[i]; }
    __shared__ int sd[256];
    sd[t] = v; __syncthreads();
    for (int off = 128; off > 0; off >>= 1) { if (t < off) sd[t] += sd[t + off]; __syncthreads(); }
    if (t == 0) bsums[b] = sd[0];
}

// scan3 with inline block-offset scan (kills the old scan2 kernel)
__global__ __launch_bounds__(256) void scan3(const int* __restrict__ deg, const int* __restrict__ bsums,
                                             int* __restrict__ rowptr, int* __restrict__ cursor) {
    int b = blockIdx.x, t = threadIdx.x;
    int boff = 0;
    for (int j = 0; j < b; j++) boff += bsums[j];   // uniform scalar loop, <=97 iters
    int base = b * 1024 + t * 4;
    int d0 = 0, d1 = 0, d2 = 0, d3 = 0;
    if (base     < NN) d0 = deg[base];
    if (base + 1 < NN) d1 = deg[base + 1];
    if (base + 2 < NN) d2 = deg[base + 2];
    if (base + 3 < NN) d3 = deg[base + 3];
    int tsum = d0 + d1 + d2 + d3;
    __shared__ int sd[256];
    sd[t] = tsum; __syncthreads();
    for (int off = 1; off < 256; off <<= 1) {
        int a = (t >= off) ? sd[t - off] : 0;
        __syncthreads();
        sd[t] += a;
        __syncthreads();
    }
    int exc = sd[t] - tsum + boff;
    int p0 = exc, p1 = exc + d0, p2 = exc + d0 + d1, p3 = exc + d0 + d1 + d2;
    if (base     < NN) { rowptr[base]     = p0; cursor[base]     = p0; }
    if (base + 1 < NN) { rowptr[base + 1] = p1; cursor[base + 1] = p1; }
    if (base + 2 < NN) { rowptr[base + 2] = p2; cursor[base + 2] = p2; }
    if (base + 3 < NN) { rowptr[base + 3] = p3; cursor[base + 3] = p3; }
    if (b == 0 && t == 0) rowptr[NN] = EE;
}

__global__ __launch_bounds__(256) void fill_kernel(const int* __restrict__ src, const int* __restrict__ dst,
                                                   int* __restrict__ cursor, int* __restrict__ elist) {
    int e = blockIdx.x * 256 + threadIdx.x;
    if (e < EE) {
        int p = atomicAdd(&cursor[dst[e]], 1);
        elist[p] = src[e];
    }
}

// ---------------- agg (path A): wave per node, 2 edges per load instr, 4 in flight ----------------
// writes bf16 agg row i into d_out at byte offset i*512.
__global__ __launch_bounds__(256) void agg_a(
    const unsigned short* __restrict__ h1b,
    const int* __restrict__ rowptr, const int* __restrict__ elist, float* __restrict__ out)
{
    int i = blockIdx.x * 4 + (threadIdx.x >> 6);
    if (i >= NN) return;
    int lane = threadIdx.x & 63;
    int half = lane >> 5, j = lane & 31;
    int beg = rowptr[i], end = rowptr[i + 1];
    float a0 = -INFINITY, a1 = -INFINITY, a2 = -INFINITY, a3 = -INFINITY;
    int e = beg;
    for (; e + 4 <= end; e += 4) {
        int s0 = elist[e], s1 = elist[e + 1], s2 = elist[e + 2], s3 = elist[e + 3];
        int rA = half ? s1 : s0;
        int rB = half ? s3 : s2;
        us4 pA = *(const us4*)(h1b + rA * DD + j * 4);
        us4 pB = *(const us4*)(h1b + rB * DD + j * 4);
        a0 = fmaxf(a0, fmaxf(__uint_as_float((unsigned)pA[0] << 16), __uint_as_float((unsigned)pB[0] << 16)));
        a1 = fmaxf(a1, fmaxf(__uint_as_float((unsigned)pA[1] << 16), __uint_as_float((unsigned)pB[1] << 16)));
        a2 = fmaxf(a2, fmaxf(__uint_as_float((unsigned)pA[2] << 16), __uint_as_float((unsigned)pB[2] << 16)));
        a3 = fmaxf(a3, fmaxf(__uint_as_float((unsigned)pA[3] << 16), __uint_as_float((unsigned)pB[3] << 16)));
    }
    for (; e < end; e += 2) {
        int s0 = elist[e];
        int s1 = (e + 1 < end) ? elist[e + 1] : s0;
        int r = half ? s1 : s0;
        us4 p = *(const us4*)(h1b + r * DD + j * 4);
        a0 = fmaxf(a0, __uint_as_float((unsigned)p[0] << 16));
        a1 = fmaxf(a1, __uint_as_float((unsigned)p[1] << 16));
        a2 = fmaxf(a2, __uint_as_float((unsigned)p[2] << 16));
        a3 = fmaxf(a3, __uint_as_float((unsigned)p[3] << 16));
    }
    a0 = fmaxf(a0, __shfl_xor(a0, 32, 64));
    a1 = fmaxf(a1, __shfl_xor(a1, 32, 64));
    a2 = fmaxf(a2, __shfl_xor(a2, 32, 64));
    a3 = fmaxf(a3, __shfl_xor(a3, 32, 64));
    if (half == 0) {
        us4 r = { 0, 0, 0, 0 };
        if (end > beg) {
            r[0] = (unsigned short)(__float_as_uint(a0) >> 16);
            r[1] = (unsigned short)(__float_as_uint(a1) >> 16);
            r[2] = (unsigned short)(__float_as_uint(a2) >> 16);
            r[3] = (unsigned short)(__float_as_uint(a3) >> 16);
        }
        *(us4*)((unsigned short*)((char*)out + (size_t)i * 512) + j * 4) = r;
    }
}

// ---------------- gemm (path A v2): 64 rows/block, A-tile in LDS, B-frags from global wb ----------------
// h2 = relu(x + agg@wl^T + bl + h1@wr^T); agg read from d_out slots, h2 written over them.
#define USTR 264   // short stride (528 B); lane-stride 132 dwords — measured conflict-free class
__global__ __launch_bounds__(256) void gemm_a(
    const float* __restrict__ X, const unsigned short* __restrict__ h1b,
    const unsigned short* __restrict__ wb, const float* __restrict__ blv,
    float* __restrict__ out)
{
    __shared__ unsigned short sU[64 * USTR];   // 33.8 KB
    int tid = threadIdx.x;
    int i0 = blockIdx.x * 64;

    // stage A-tile: 64 rows x 256 k (k<128: agg bf16 from out slots, k>=128: h1b)
    for (int t = tid; t < 64 * 32; t += 256) {
        int r = t >> 5, c = t & 31;
        int i = i0 + r; if (i >= NN) i = NN - 1;
        uint4 v;
        if (c < 16) v = ((const uint4*)((const char*)out + (size_t)i * 512))[c];
        else        v = ((const uint4*)(h1b + (size_t)i * DD))[c - 16];
        *(uint4*)&sU[r * USTR + c * 8] = v;
    }
    __syncthreads();

    int lane = tid & 63, wave = tid >> 6;
    int m = lane & 31, hf = lane >> 5;
    int col = wave * 32 + m;
    const unsigned short* bcol = wb + col * 256 + hf * 8;

    f32x16 acc0, acc1;
    #pragma unroll
    for (int r = 0; r < 16; r++) { acc0[r] = 0.f; acc1[r] = 0.f; }

    #pragma unroll
    for (int h = 0; h < 2; h++) {
        bf16x8 bfr[8];
        #pragma unroll
        for (int s = 0; s < 8; s++) bfr[s] = *(const bf16x8*)(bcol + h * 128 + s * 16);
        #pragma unroll
        for (int s = 0; s < 8; s++) {
            int ko = h * 128 + s * 16 + hf * 8;
            bf16x8 a0 = *(const bf16x8*)&sU[m * USTR + ko];
            bf16x8 a1 = *(const bf16x8*)&sU[(32 + m) * USTR + ko];
            acc0 = __builtin_amdgcn_mfma_f32_32x32x16_bf16(a0, bfr[s], acc0, 0, 0, 0);
            acc1 = __builtin_amdgcn_mfma_f32_32x32x16_bf16(a1, bfr[s], acc1, 0, 0, 0);
        }
    }

    // epilogue: C/D layout col=lane&31, row=(reg&3)+8*(reg>>2)+4*hf
    float blc = blv[col];
    #pragma unroll
    for (int reg = 0; reg < 16; reg++) {
        int rl = (reg & 3) + 8 * (reg >> 2) + 4 * hf;
        int ia = i0 + rl;
        int ib = i0 + 32 + rl;
        if (ia < NN) {
            float v = X[ia * DD + col] + blc + acc0[reg];
            out[ia * DD + col] = v > 0.f ? v : 0.f;
        }
        if (ib < NN) {
            float v = X[ib * DD + col] + blc + acc1[reg];
            out[ib * DD + col] = v > 0.f ? v : 0.f;
        }
    }
}

// ---------------- fallback path B: fp32 agg + LDS gemm (validated round 2) ----------------
__global__ __launch_bounds__(256) void agg_b(
    const float* __restrict__ X, const int* __restrict__ batch,
    const float* __restrict__ A1, const float* __restrict__ B1,
    const int* __restrict__ rowptr, const int* __restrict__ elist, float* __restrict__ H)
{
    int i = blockIdx.x * 2 + (threadIdx.x >> 7);
    int d = threadIdx.x & 127;
    int beg = rowptr[i], end = rowptr[i + 1];
    float acc = -INFINITY;
    int e = beg;
    for (; e + 2 <= end; e += 2) {
        int s0 = elist[e], s1 = elist[e + 1];
        int g0 = batch[s0], g1 = batch[s1];
        float v0 = fmaf(A1[g0 * DD + d], X[s0 * DD + d], B1[g0 * DD + d]);
        float v1 = fmaf(A1[g1 * DD + d], X[s1 * DD + d], B1[g1 * DD + d]);
        acc = fmaxf(acc, fmaxf(v0, v1));
    }
    for (; e < end; e++) {
        int s = elist[e]; int g = batch[s];
        acc = fmaxf(acc, fmaf(A1[g * DD + d], X[s * DD + d], B1[g * DD + d]));
    }
    if (end == beg) acc = 0.f;
    H[i * DD + d] = acc;
}

#define BM 128
#define LDT 72
__global__ __launch_bounds__(256) void gemm_b(
    const float* __restrict__ X, const int* __restrict__ batch,
    const float* __restrict__ A1, const float* __restrict__ B1,
    const float* __restrict__ wl, const float* __restrict__ blv, const float* __restrict__ wr,
    float* __restrict__ H)
{
    __shared__ unsigned short Ut[BM * LDT];
    __shared__ unsigned short Wt[DD * LDT];
    int i0 = blockIdx.x * BM;
    int tid = threadIdx.x;
    int lane = tid & 63, wave = tid >> 6;
    int wrow = (wave >> 1) * 64, wcol = (wave & 1) * 64;
    int m = lane & 31, hf = lane >> 5;

    f32x16 acc00, acc01, acc10, acc11;
    #pragma unroll
    for (int r = 0; r < 16; r++) { acc00[r] = 0.f; acc01[r] = 0.f; acc10[r] = 0.f; acc11[r] = 0.f; }

    for (int c = 0; c < 4; c++) {
        __syncthreads();
        for (int t = tid; t < BM * 16; t += 256) {
            int r = t >> 4, c4 = t & 15;
            int i = i0 + r; if (i >= NN) i = NN - 1;
            float4 v;
            if (c < 2) {
                v = ((const float4*)H)[i * 32 + c * 16 + c4];
            } else {
                int g = batch[i];
                float4 xv = ((const float4*)X)[i * 32 + (c - 2) * 16 + c4];
                float4 a = ((const float4*)A1)[g * 32 + (c - 2) * 16 + c4];
                float4 b = ((const float4*)B1)[g * 32 + (c - 2) * 16 + c4];
                v.x = fmaf(a.x, xv.x, b.x); v.y = fmaf(a.y, xv.y, b.y);
                v.z = fmaf(a.z, xv.z, b.z); v.w = fmaf(a.w, xv.w, b.w);
            }
            us4 o = { f2bf(v.x), f2bf(v.y), f2bf(v.z), f2bf(v.w) };
            *(us4*)&Ut[r * LDT + c4 * 4] = o;
        }
        {
            const float* Wsrc = (c < 2) ? wl : wr;
            int kb = (c & 1) * 16;
            for (int t = tid; t < DD * 16; t += 256) {
                int j = t >> 4, c4 = t & 15;
                float4 v = ((const float4*)Wsrc)[j * 32 + kb + c4];
                us4 o = { f2bf(v.x), f2bf(v.y), f2bf(v.z), f2bf(v.w) };
                *(us4*)&Wt[j * LDT + c4 * 4] = o;
            }
        }
        __syncthreads();
        #pragma unroll
        for (int kk = 0; kk < 4; kk++) {
            int kb2 = kk * 16 + hf * 8;
            bf16x8 a0 = *(const bf16x8*)&Ut[(wrow      + m) * LDT + kb2];
            bf16x8 a1 = *(const bf16x8*)&Ut[(wrow + 32 + m) * LDT + kb2];
            bf16x8 b0 = *(const bf16x8*)&Wt[(wcol      + m) * LDT + kb2];
            bf16x8 b1 = *(const bf16x8*)&Wt[(wcol + 32 + m) * LDT + kb2];
            acc00 = __builtin_amdgcn_mfma_f32_32x32x16_bf16(a0, b0, acc00, 0, 0, 0);
            acc01 = __builtin_amdgcn_mfma_f32_32x32x16_bf16(a0, b1, acc01, 0, 0, 0);
            acc10 = __builtin_amdgcn_mfma_f32_32x32x16_bf16(a1, b0, acc10, 0, 0, 0);
            acc11 = __builtin_amdgcn_mfma_f32_32x32x16_bf16(a1, b1, acc11, 0, 0, 0);
        }
    }

    int col0 = wcol + m, col1 = wcol + 32 + m;
    float bl0 = blv[col0], bl1 = blv[col1];
    #pragma unroll
    for (int reg = 0; reg < 16; reg++) {
        int rl = (reg & 3) + 8 * (reg >> 2) + 4 * hf;
        int ia = i0 + wrow + rl;
        int ib = i0 + wrow + 32 + rl;
        if (ia < NN) {
            float v0 = X[ia * DD + col0] + bl0 + acc00[reg];
            float v1 = X[ia * DD + col1] + bl1 + acc01[reg];
            H[ia * DD + col0] = v0 > 0.f ? v0 : 0.f;
            H[ia * DD + col1] = v1 > 0.f ? v1 : 0.f;
        }
        if (ib < NN) {
            float v0 = X[ib * DD + col0] + bl0 + acc10[reg];
            float v1 = X[ib * DD + col1] + bl1 + acc11[reg];
            H[ib * DD + col0] = v0 > 0.f ? v0 : 0.f;
            H[ib * DD + col1] = v1 > 0.f ? v1 : 0.f;
        }
    }
}

extern "C" void kernel_launch(void* const* d_in, const int* in_sizes, int n_in,
                              void* d_out, int out_size, void* d_ws, size_t ws_size,
                              hipStream_t stream) {
    const float* x    = (const float*)d_in[0];
    const int*   ei   = (const int*)d_in[1];
    const int*   batch= (const int*)d_in[2];
    const float* n1w  = (const float*)d_in[3];
    const float* n1b  = (const float*)d_in[4];
    const float* n1ms = (const float*)d_in[5];
    const float* n2w  = (const float*)d_in[6];
    const float* n2b  = (const float*)d_in[7];
    const float* n2ms = (const float*)d_in[8];
    const float* wl   = (const float*)d_in[9];
    const float* bl   = (const float*)d_in[10];
    const float* wr   = (const float*)d_in[11];
    float* out = (float*)d_out;

    char* w = (char*)d_ws;
    float* A1     = (float*)(w + OFF_A1);
    float* B1     = (float*)(w + OFF_B1);
    float* A2     = (float*)(w + OFF_A2);
    float* B2     = (float*)(w + OFF_B2);
    int*   deg    = (int*)(w + OFF_DEG);
    int*   rowptr = (int*)(w + OFF_ROWPTR);
    int*   cursor = (int*)(w + OFF_CURSOR);
    int*   bsums  = (int*)(w + OFF_BSUMS);
    int*   elist  = (int*)(w + OFF_ELIST);
    unsigned short* wb  = (unsigned short*)(w + OFF_WB);
    unsigned short* h1b = (unsigned short*)(w + OFF_H1B);

    const int* src = ei;
    const int* dst = ei + EE;
    const int NB1024 = (NN + 1023) / 1024;
    bool bigws = (ws_size >= WS_NEED_A);

    hipMemsetAsync(deg, 0, NN * sizeof(int), stream);

    stats_kernel<<<GG + 2, 512, 0, stream>>>(x, batch, n1w, n1b, n1ms, A1, B1,
                                             bigws ? h1b : (unsigned short*)nullptr,
                                             bigws ? wb : (unsigned short*)nullptr,
                                             wl, wr, 1);

    deg_kernel<<<(EE + 255) / 256, 256, 0, stream>>>(dst, deg);
    scan1<<<NB1024, 256, 0, stream>>>(deg, bsums);
    scan3<<<NB1024, 256, 0, stream>>>(deg, bsums, rowptr, cursor);
    fill_kernel<<<(EE + 255) / 256, 256, 0, stream>>>(src, dst, cursor, elist);

    if (bigws) {
        agg_a<<<(NN + 3) / 4, 256, 0, stream>>>(h1b, rowptr, elist, out);
        gemm_a<<<(NN + 63) / 64, 256, 0, stream>>>(x, h1b, wb, bl, out);
    } else {
        agg_b<<<NN / 2, 256, 0, stream>>>(x, batch, A1, B1, rowptr, elist, out);
        gemm_b<<<(NN + BM - 1) / BM, 256, 0, stream>>>(x, batch, A1, B1, wl, bl, wr, out);
    }

    stats_kernel<<<GG + 2, 512, 0, stream>>>(out, batch, n2w, n2b, n2ms, A2, B2,
                                             (unsigned short*)nullptr, (unsigned short*)nullptr,
                                             (const float*)nullptr, (const float*)nullptr, 2);
}